// Round 13
// baseline (405.321 us; speedup 1.0000x reference)
//
#include <hip/hip_runtime.h>
#include <cstdint>

// Geometry: B=8, C=512, H=37, W=50, HW=1850, BHW=14800, anchors A=16650, K1=400
#define BHW_ 14800
#define CHW_ 947200
#define A_   16650
#define OCLS 532800
#define OBOX 799200
#define OKEEP 812000
#define NSTEP 144     // 16 cc-chunks * 9 khw

typedef unsigned int u32;
typedef unsigned long long u64;
typedef _Float16 f16x8 __attribute__((ext_vector_type(8)));
typedef float f32x4 __attribute__((ext_vector_type(4)));

__device__ __forceinline__ unsigned int fkey(float f){
  unsigned int u = __float_as_uint(f);
  return (u & 0x80000000u) ? ~u : (u | 0x80000000u);
}

// anchors exactly as numpy: w=(16*s)/sqrt(r), h=(16*s)*sqrt(r), f64 then f32 cast
__device__ __forceinline__ void anchor_corners(int x, int y, int kk,
                                               float& ax1, float& ay1, float& ax2, float& ay2){
  int si = kk % 3, ri = kk / 3;
  double rv = (ri==0) ? 0.5 : ((ri==1) ? 1.0 : 2.0);
  double sr = sqrt(rv);
  double fs = 128.0 * (double)(si+1);
  double h = fs * sr, w = fs / sr;
  double cx = (double)(x*16 + 8), cy = (double)(y*16 + 8);
  ax1 = (float)(cx - w*0.5); ay1 = (float)(cy - h*0.5);
  ax2 = (float)(cx + w*0.5); ay2 = (float)(cy + h*0.5);
}

// --- weight split (coalesced: khw-fastest; one thread -> hi AND lo chunks) + head-pack tail blocks.
// WfA chunk index = (s*4+ot)*1024 + (l4g*2+hl)*128 + o7 ; 8 f16 (j over ci octet).
__global__ __launch_bounds__(256) void k_split_w(const float* __restrict__ w,
                                                 const float* __restrict__ cw, const float* __restrict__ cb,
                                                 const float* __restrict__ ow, const float* __restrict__ ob,
                                                 _Float16* __restrict__ WfA,
                                                 float* __restrict__ hwp, float* __restrict__ hb){
  int bid = blockIdx.x;
  if (bid < 1152){
    int u = bid*256 + threadIdx.x;  // < 294912 = 16*4*4*128*9
    int khw = u % 9;
    int v = u / 9;                  // < 32768
    int o7  = v & 127;
    int l4g = (v >> 7) & 3;
    int ot  = (v >> 9) & 3;
    int cc  = v >> 11;              // 0..15
    int o = ot*128 + o7;
    int s = cc*9 + khw;
    f16x8 hi, lo;
    #pragma unroll
    for (int j = 0; j < 8; ++j){
      float val = w[(size_t)(o*512 + cc*32 + l4g*8 + j)*9 + khw];
      _Float16 h = (_Float16)val;
      hi[j] = h; lo[j] = (_Float16)(val - (float)h);
    }
    size_t base = ((size_t)(s*4 + ot)*1024 + (size_t)(l4g*2)*128 + o7)*8;
    *(f16x8*)&WfA[base] = hi;
    *(f16x8*)&WfA[base + 1024] = lo;   // +128 chunks (hl=1)
  } else {
    int t = (bid - 1152)*256 + threadIdx.x;  // < 32768
    if (t < 64) hb[t] = (t < 18) ? cb[t] : (t < 54 ? ob[t-18] : 0.f);
    int r = t & 63, ci = t >> 6;
    hwp[t] = (r < 18) ? cw[r*512 + ci] : (r < 54 ? ow[(r-18)*512 + ci] : 0.f);
  }
}

// --- feature split -> padded position-major hi/lo f16 planes Fp{h,l}[b][39][52][512]
// blocks <928: LDS-tiled transpose (interior). blocks >=928: zero the pad ring.
__global__ __launch_bounds__(256) void k_split_f(const float* __restrict__ feat,
                                                 _Float16* __restrict__ Fph, _Float16* __restrict__ Fpl){
  int bid = blockIdx.x;
  if (bid < 928){
    __shared__ float T[64][129];
    int ct = bid & 3; int pt = (bid >> 2) % 29; int b = bid / 116;
    int tid = threadIdx.x;
    #pragma unroll
    for (int it = 0; it < 32; ++it){
      int idx = it*256 + tid;
      int c = idx >> 6, p = idx & 63;
      int pos = pt*64 + p;
      T[p][c] = (pos < 1850) ? feat[(size_t)(b*512 + ct*128 + c)*1850 + pos] : 0.f;
    }
    __syncthreads();
    #pragma unroll
    for (int it = 0; it < 4; ++it){
      int idx = it*256 + tid;
      int p = idx >> 4, c8 = (idx & 15) * 8;
      int pos = pt*64 + p;
      if (pos < 1850){
        int y = pos/50, x = pos - y*50;
        size_t off = ((size_t)(b*39 + y + 1)*52 + (x + 1))*512 + ct*128 + c8;
        f16x8 hv, lv;
        #pragma unroll
        for (int j = 0; j < 8; ++j){
          float v = T[p][c8 + j];
          _Float16 h = (_Float16)v;
          hv[j] = h; lv[j] = (_Float16)(v - (float)h);
        }
        *(f16x8*)&Fph[off] = hv;
        *(f16x8*)&Fpl[off] = lv;
      }
    }
  } else {
    int t = (bid - 928)*256 + threadIdx.x;   // < 182272
    if (t >= 182272) return;
    _Float16* base = (t < 91136) ? Fph : Fpl;
    int u = (t < 91136) ? t : t - 91136;
    int c8 = (u & 63) * 8;
    int pu = u >> 6;
    int b = pu / 178, p = pu - b*178;
    int yp, xp;
    if (p < 52){ yp = 0; xp = p; }
    else if (p < 104){ yp = 38; xp = p - 52; }
    else if (p < 141){ yp = p - 104 + 1; xp = 0; }
    else { yp = p - 141 + 1; xp = 51; }
    f16x8 z = {};
    *(f16x8*)&base[((size_t)(b*39 + yp)*52 + xp)*512 + c8] = z;
  }
}

// --- 3x3 conv, implicit GEMM, f16x2-split MFMA. 512 threads = 8 waves of 64o x 32n.
// BM=BN=128, BK=32. ALL staging via global_load_lds (A: 2x16B dbuf, B: 2x16B triple-buffer,
// staged 2 steps ahead). Counted s_waitcnt vmcnt(2) + raw s_barrier per step — staging
// stays in flight across barriers. 80KB LDS -> 2 blocks/CU (~16 waves/CU).
__global__ __launch_bounds__(512, 2) void k_conv3_mfma(const _Float16* __restrict__ Fph,
                                                       const _Float16* __restrict__ Fpl,
                                                       const _Float16* __restrict__ WfA,
                                                       const float* __restrict__ mdb,
                                                       float* __restrict__ out0){
  __shared__ _Float16 Abuf[2][8192];   // 16KB x2
  __shared__ _Float16 Bbuf[3][8192];   // 16KB x3  -> 80KB total
  const int tid = threadIdx.x;
  // otile-major XCD grouping: 2 XCDs share each otile's A slab (2.36MB, L2-fits)
  int flat = blockIdx.x;
  int xcd = flat & 7, sub = flat >> 3;
  int swz = xcd * 58 + sub;
  int otile = swz / 116;
  int ntile = swz - otile*116;

  // B staging decode: pos = tid&127, k-octet group kg8 = tid>>7 (0..3)
  const int bpos = tid & 127, kg8 = tid >> 7;
  int n = ntile*128 + bpos; if (n >= BHW_) n = BHW_ - 1;
  int nb = n/1850; int rem = n - nb*1850; int ny = rem/50; int nx = rem - ny*50;
  const size_t pbase = ((size_t)(nb*39 + ny + 1)*52 + (nx + 1))*512 + kg8*8;

  auto stageA = [&](int s, int ab){
    const _Float16* g = WfA + ((size_t)(s*4 + otile)*1024 + tid)*8;
    _Float16* la = &Abuf[ab][(size_t)tid*8];
    __builtin_amdgcn_global_load_lds((const __attribute__((address_space(1))) void*)g,
                                     (__attribute__((address_space(3))) void*)la, 16, 0, 0);
    __builtin_amdgcn_global_load_lds((const __attribute__((address_space(1))) void*)(g + 4096),
                                     (__attribute__((address_space(3))) void*)(la + 4096), 16, 0, 0);
  };
  auto stageB = [&](int s, int bb){
    int cc = s/9, khw = s - cc*9;
    int dy = khw/3 - 1, dx = khw - (khw/3)*3 - 1;
    size_t src = pbase + (size_t)((dy*52 + dx)*512 + cc*32);
    _Float16* lb = &Bbuf[bb][(size_t)((kg8*2)*128 + bpos)*8];
    __builtin_amdgcn_global_load_lds((const __attribute__((address_space(1))) void*)(Fph + src),
                                     (__attribute__((address_space(3))) void*)lb, 16, 0, 0);
    __builtin_amdgcn_global_load_lds((const __attribute__((address_space(1))) void*)(Fpl + src),
                                     (__attribute__((address_space(3))) void*)(lb + 1024), 16, 0, 0);
  };

  // compute role: 8 waves -> wm = w>>2 (o-half), wn = w&3 (n-quarter)
  const int w = tid >> 6, lane = tid & 63;
  const int wm = w >> 2, wn = w & 3;
  const int l15 = lane & 15, l4 = lane >> 4;

  f32x4 acc[4][2] = {};

  auto compute = [&](int ab, int bb){
    f16x8 ah[4], al[4], bh[2], bl[2];
    #pragma unroll
    for (int mf = 0; mf < 4; ++mf){
      int m = wm*64 + mf*16 + l15;
      ah[mf] = *(const f16x8*)&Abuf[ab][(size_t)((l4*2 + 0)*128 + m)*8];
      al[mf] = *(const f16x8*)&Abuf[ab][(size_t)((l4*2 + 1)*128 + m)*8];
    }
    #pragma unroll
    for (int nf = 0; nf < 2; ++nf){
      int nn = wn*32 + nf*16 + l15;
      bh[nf] = *(const f16x8*)&Bbuf[bb][(size_t)((l4*2 + 0)*128 + nn)*8];
      bl[nf] = *(const f16x8*)&Bbuf[bb][(size_t)((l4*2 + 1)*128 + nn)*8];
    }
    #pragma unroll
    for (int mf = 0; mf < 4; ++mf)
      #pragma unroll
      for (int nf = 0; nf < 2; ++nf){
        acc[mf][nf] = __builtin_amdgcn_mfma_f32_16x16x32_f16(ah[mf], bh[nf], acc[mf][nf], 0,0,0);
        acc[mf][nf] = __builtin_amdgcn_mfma_f32_16x16x32_f16(ah[mf], bl[nf], acc[mf][nf], 0,0,0);
        acc[mf][nf] = __builtin_amdgcn_mfma_f32_16x16x32_f16(al[mf], bh[nf], acc[mf][nf], 0,0,0);
      }
  };

  // prologue: A0, B0, B1 in flight (6 ops); vmcnt(2) drains A0,B0; B1 stays in flight
  stageA(0, 0);
  stageB(0, 0);
  stageB(1, 1);
  __builtin_amdgcn_sched_barrier(0);
  asm volatile("s_waitcnt vmcnt(2)" ::: "memory");
  __builtin_amdgcn_s_barrier();

  for (int s = 0; s < NSTEP; ++s){
    if (s + 1 < NSTEP) stageA(s+1, (s+1) & 1);
    if (s + 2 < NSTEP) stageB(s+2, (s+2) % 3);   // overwrites buffer read at s-1 (safe post-barrier)
    __builtin_amdgcn_sched_barrier(0);
    compute(s & 1, s % 3);
    __builtin_amdgcn_sched_barrier(0);
    // in-flight: B(s+1)[2] + A(s+1)[2] + B(s+2)[2]; keep only newest 2 = B(s+2)
    if (s + 2 < NSTEP) asm volatile("s_waitcnt vmcnt(2)" ::: "memory");
    else               asm volatile("s_waitcnt vmcnt(0)" ::: "memory");
    __builtin_amdgcn_s_barrier();
  }

  // epilogue: D row = l4*4 + r, col = l15 within each 16x16 frag
  #pragma unroll
  for (int nf = 0; nf < 2; ++nf){
    int ng = ntile*128 + wn*32 + nf*16 + l15;
    if (ng >= BHW_) continue;
    int b2 = ng/1850; int rem2 = ng - b2*1850;
    #pragma unroll
    for (int mf = 0; mf < 4; ++mf){
      int o0 = otile*128 + wm*64 + mf*16 + l4*4;
      #pragma unroll
      for (int r = 0; r < 4; ++r){
        out0[(size_t)b2*CHW_ + (size_t)(o0 + r)*1850 + rem2] = acc[mf][nf][r] + mdb[o0 + r];
      }
    }
  }
}

// --- BN stats per channel (double accumulation)
__global__ __launch_bounds__(256) void k_bnstats(const float* __restrict__ out0,
                                                 float* __restrict__ bnm, float* __restrict__ bnr){
  __shared__ double s1[256], s2[256];
  int c = blockIdx.x, tid = threadIdx.x;
  double a = 0.0, b = 0.0;
  for (int i = tid; i < BHW_; i += 256){
    int bb = i / 1850; int r = i - bb*1850;
    float v = out0[(size_t)bb*CHW_ + (size_t)c*1850 + r];
    a += (double)v; b += (double)v*(double)v;
  }
  s1[tid] = a; s2[tid] = b; __syncthreads();
  for (int off = 128; off; off >>= 1){
    if (tid < off){ s1[tid] += s1[tid+off]; s2[tid] += s2[tid+off]; }
    __syncthreads();
  }
  if (tid == 0){
    double m = s1[0] / 14800.0;
    double var = s2[0] / 14800.0 - m*m;
    bnm[c] = (float)m;
    bnr[c] = 1.0f / sqrtf((float)var + 1e-5f);
  }
}

// --- head GEMM with fused BN+ReLU staging and fused score-key emission
__global__ __launch_bounds__(256) void k_heads(const float* __restrict__ out0, const float* __restrict__ hwp,
                                               const float* __restrict__ hb, const float* __restrict__ bnm,
                                               const float* __restrict__ bnr, const float* __restrict__ gamma,
                                               const float* __restrict__ beta, float* __restrict__ dout,
                                               u64* __restrict__ keys){
#pragma clang fp contract(off)
  __shared__ float As[16][64];
  __shared__ float Bs[16][64];
  __shared__ int sb[64], sy[64], sx[64];
  int tid = threadIdx.x; int ntile = blockIdx.x;
  if (tid < 64){
    int n = ntile*64 + tid;
    if (n < BHW_){ int b = n/1850; int r = n - b*1850; int y = r/50; sb[tid]=b; sy[tid]=y; sx[tid]=r - y*50; }
    else { sb[tid] = -1; sy[tid] = 0; sx[tid] = 0; }
  }
  __syncthreads();
  float acc[4][4] = {};
  const int tx = tid & 15, ty = tid >> 4;
  const int lci = tid >> 4, lo4 = (tid & 15) * 4;
  for (int ct = 0; ct < 32; ++ct){
    int cib = ct*16;
    float4 av = *(const float4*)(hwp + (cib + lci)*64 + lo4);
    float4 bv; float* bp = (float*)&bv;
    int cig = cib + lci;
    float gm = gamma[cig], mm = bnm[cig], rr = bnr[cig], bt = beta[cig];
    #pragma unroll
    for (int j = 0; j < 4; ++j){
      int nn = lo4 + j; int b = sb[nn];
      float v = 0.f;
      if (b >= 0){
        float x = out0[(size_t)b*CHW_ + (size_t)cig*1850 + sy[nn]*50 + sx[nn]];
        float y = gm * (x - mm);
        y = y * rr;
        y = y + bt;
        v = fmaxf(y, 0.f);
      }
      bp[j] = v;
    }
    __syncthreads();
    *(float4*)&As[lci][lo4] = av;
    *(float4*)&Bs[lci][lo4] = bv;
    __syncthreads();
    #pragma unroll
    for (int k = 0; k < 16; ++k){
      float4 a4 = *(const float4*)&As[k][ty*4];
      float4 b4 = *(const float4*)&Bs[k][tx*4];
      const float* ap = (const float*)&a4; const float* bq = (const float*)&b4;
      #pragma unroll
      for (int i = 0; i < 4; ++i)
        #pragma unroll
        for (int j = 0; j < 4; ++j)
          acc[i][j] = fmaf(ap[i], bq[j], acc[i][j]);
    }
  }
  #pragma unroll
  for (int i = 0; i < 4; ++i){
    int r = ty*4 + i;
    if (r >= 54) continue;
    float bias = hb[r];
    #pragma unroll
    for (int j = 0; j < 4; ++j){
      int nl = tx*4 + j;
      int b = sb[nl];
      if (b < 0) continue;
      int pos = sy[nl]*50 + sx[nl];
      float v = acc[i][j] + bias;
      if (r < 18){
        int kk = r >> 1, cc = r & 1;
        dout[OCLS + ((size_t)b*A_ + pos*9 + kk)*2 + cc] = v;
      } else {
        int r2 = r - 18, kk = r2 >> 2, cc = r2 & 3;
        dout[((size_t)b*A_ + pos*9 + kk)*4 + cc] = v;
      }
    }
  }
  if (ty < 5){
    #pragma unroll
    for (int i = 0; i < 4; i += 2){
      int r = ty*4 + i;
      if (r >= 18) continue;
      int kk = r >> 1;
      float b0 = hb[r], b1 = hb[r+1];
      #pragma unroll
      for (int j = 0; j < 4; ++j){
        int nl = tx*4 + j;
        int b = sb[nl];
        if (b < 0) continue;
        float c0 = acc[i][j] + b0;
        float c1 = acc[i+1][j] + b1;
        float d = c1 - c0;
        float ax1, ay1, ax2, ay2;
        anchor_corners(sx[nl], sy[nl], kk, ax1, ay1, ax2, ay2);
        bool valid = (ax1 >= 0.f) && (ay1 >= 0.f) && (ax2 < 800.f) && (ay2 < 592.f);
        unsigned a = (unsigned)(sy[nl]*50 + sx[nl])*9u + (unsigned)kk;
        u64 key = valid ? (((u64)fkey(d) << 32) | (u64)(~a)) : 0ull;
        keys[(size_t)b*A_ + a] = key;
      }
    }
  }
}

// --- fused deterministic post: 2-level histogram threshold -> LDS compact -> LDS rank
//     -> decode -> adjacency NMS. NO intra-kernel global scratch (r8 lesson).
__global__ __launch_bounds__(1024) void k_post(const u64* __restrict__ keys,
                                               float* __restrict__ dout){
#pragma clang fp contract(off)
  __shared__ u32 hist[4096];
  __shared__ u32 sp[1024];
  __shared__ u64 selbuf[4096];
  __shared__ u64 stopk[400];
  __shared__ u32 adj32[6400];
  __shared__ float X1[400], Y1[400], X2[400], Y2[400], AR[400];
  __shared__ u32 ssup[13];
  __shared__ u32 s_t1, s_base1, s_t2, scnt;
  int b = blockIdx.x, tid = threadIdx.x;
  const u64* kb = keys + (size_t)b*A_;

  // ---- pass 1: histogram of key bits [52,63] over nonzero keys
  for (int i = tid; i < 4096; i += 1024) hist[i] = 0u;
  if (tid == 0) scnt = 0u;
  __syncthreads();
  for (int i = tid; i < A_; i += 1024){
    u64 k = kb[i];
    if (k) atomicAdd(&hist[(u32)(k >> 52)], 1u);
  }
  __syncthreads();
  {
    u32 p = hist[tid*4] + hist[tid*4+1] + hist[tid*4+2] + hist[tid*4+3];
    sp[tid] = p; __syncthreads();
    for (int off = 1; off < 1024; off <<= 1){
      u32 v = sp[tid] + ((tid + off < 1024) ? sp[tid + off] : 0u);
      __syncthreads(); sp[tid] = v; __syncthreads();
    }
    if (sp[tid] >= 400u && (tid == 1023 || sp[tid+1] < 400u)){
      u32 cum = (tid == 1023) ? 0u : sp[tid+1];
      for (int bb = tid*4 + 3; bb >= tid*4; --bb){
        cum += hist[bb];
        if (cum >= 400u){ s_t1 = (u32)bb; s_base1 = cum - hist[bb]; break; }
      }
    }
  }
  __syncthreads();
  const u32 t1 = s_t1;
  const u32 need2 = 400u - s_base1;   // >= 1

  // ---- pass 2: histogram of bits [40,51] among keys whose top-12 == t1
  __syncthreads();
  for (int i = tid; i < 4096; i += 1024) hist[i] = 0u;
  __syncthreads();
  for (int i = tid; i < A_; i += 1024){
    u64 k = kb[i];
    if (k && (u32)(k >> 52) == t1) atomicAdd(&hist[(u32)(k >> 40) & 0xFFFu], 1u);
  }
  __syncthreads();
  {
    u32 p = hist[tid*4] + hist[tid*4+1] + hist[tid*4+2] + hist[tid*4+3];
    sp[tid] = p; __syncthreads();
    for (int off = 1; off < 1024; off <<= 1){
      u32 v = sp[tid] + ((tid + off < 1024) ? sp[tid + off] : 0u);
      __syncthreads(); sp[tid] = v; __syncthreads();
    }
    if (sp[tid] >= need2 && (tid == 1023 || sp[tid+1] < need2)){
      u32 cum = (tid == 1023) ? 0u : sp[tid+1];
      for (int bb = tid*4 + 3; bb >= tid*4; --bb){
        cum += hist[bb];
        if (cum >= need2){ s_t2 = (u32)bb; break; }
      }
    }
  }
  __syncthreads();
  const u32 t2 = s_t2;

  // ---- compact selected keys into LDS (order nondeterministic; rank fixes it)
  for (int i = tid; i < A_; i += 1024){
    u64 k = kb[i];
    if (!k) continue;
    u32 top = (u32)(k >> 52);
    bool sel = (top > t1) || (top == t1 && ((u32)(k >> 40) & 0xFFFu) >= t2);
    if (sel){
      u32 pidx = atomicAdd(&scnt, 1u);
      if (pidx < 4096u) selbuf[pidx] = k;
    }
  }
  __syncthreads();
  int C = min((int)scnt, 4096);

  // ---- exact in-LDS rank-by-counting -> ordered top-400
  for (int i = tid; i < C; i += 1024){
    u64 my = selbuf[i];
    int c = 0;
    for (int j = 0; j < C; ++j) c += (selbuf[j] > my) ? 1 : 0;
    if (c < 400) stopk[c] = my;
  }
  __syncthreads();

  // ---- decode boxes + adjacency bitmask
  for (int i = tid; i < 6400; i += 1024) adj32[i] = 0u;
  if (tid < 400){
    u64 key = stopk[tid];
    unsigned a = ~(unsigned)(key & 0xFFFFFFFFull);
    int pos = a/9; int kk = a - pos*9;
    int y = pos/50; int x = pos - y*50;
    float ax1, ay1, ax2, ay2;
    anchor_corners(x, y, kk, ax1, ay1, ax2, ay2);
    float xa = (ax1 + ax2) * 0.5f;
    float ya = (ay1 + ay2) * 0.5f;
    float wa = ax2 - ax1 + 1.0f;
    float ha = ay2 - ay1 + 1.0f;
    const float* t = dout + ((size_t)b*A_ + a)*4;
    float t0 = t[0], t1f = t[1], t2f = t[2], t3 = t[3];
    float xc = t0 * wa + xa;
    float yc = t1f * ha + ya;
    float bw = wa * expf(t2f);
    float bh = ha * expf(t3);
    float bx1 = xc - bw*0.5f, by1 = yc - bh*0.5f;
    float bx2 = xc + bw*0.5f, by2 = yc + bh*0.5f;
    float* bo = dout + OBOX + ((size_t)b*400 + tid)*4;
    bo[0] = bx1; bo[1] = by1; bo[2] = bx2; bo[3] = by2;
    float tx1 = truncf(bx1), ty1 = truncf(by1), tx2 = truncf(bx2), ty2 = truncf(by2);
    X1[tid] = tx1; Y1[tid] = ty1; X2[tid] = tx2; Y2[tid] = ty2;
    AR[tid] = (tx2 - tx1 + 1.0f) * (ty2 - ty1 + 1.0f);
  }
  __syncthreads();
  for (int q = tid; q < 160000; q += 1024){
    int i = q / 400, j = q - i*400;
    if (j > i){
      float iw = fminf(X2[i], X2[j]) - fmaxf(X1[i], X1[j]) + 1.0f; iw = fmaxf(iw, 0.f);
      float ih = fminf(Y2[i], Y2[j]) - fmaxf(Y1[i], Y1[j]) + 1.0f; ih = fmaxf(ih, 0.f);
      float inter = iw * ih;
      float iou = inter / ((AR[i] + AR[j]) - inter);
      if (iou > 0.6f) atomicOr(&adj32[i*16 + (j >> 5)], 1u << (j & 31));
    }
  }
  __syncthreads();
  // ---- serial greedy over the adjacency bitmask (wave 0, lockstep)
  if (tid < 64){
    u32 sup = 0;
    for (int i = 0; i < 399; ++i){
      u32 a = (tid < 13) ? adj32[i*16 + tid] : 0u;
      u32 so = __shfl(sup, i >> 5);
      if (!((so >> (i & 31)) & 1u)) sup |= a;
    }
    if (tid < 13) ssup[tid] = sup;
  }
  __syncthreads();
  if (tid < 400)
    dout[OKEEP + (size_t)b*400 + tid] = ((ssup[tid >> 5] >> (tid & 31)) & 1u) ? 0.f : 1.f;
}

extern "C" void kernel_launch(void* const* d_in, const int* in_sizes, int n_in,
                              void* d_out, int out_size, void* d_ws, size_t ws_size,
                              hipStream_t stream){
  const float* feat  = (const float*)d_in[0];
  const float* mdw   = (const float*)d_in[1];
  const float* mdb   = (const float*)d_in[2];
  const float* gamma = (const float*)d_in[3];
  const float* beta  = (const float*)d_in[4];
  const float* clsw  = (const float*)d_in[5];
  const float* clsb  = (const float*)d_in[6];
  const float* offw  = (const float*)d_in[7];
  const float* offb  = (const float*)d_in[8];
  float* dout = (float*)d_out;
  float* ws = (float*)d_ws;

  float* out0 = ws;                                   // 7,577,600 f32
  _Float16* WfA = (_Float16*)(out0 + 7577600);        // 4,718,592 f16
  _Float16* Fph = (_Float16*)(out0 + 7577600 + 2359296);           // 8,306,688 f16
  _Float16* Fpl = (_Float16*)(out0 + 7577600 + 2359296 + 4153344); // 8,306,688 f16
  float* hwp = out0 + 18243584;                       // 32,768
  float* hb  = hwp + 32768;                           // 64
  float* bnm = hb + 64;                               // 512
  float* bnr = bnm + 512;                             // 512
  u64* keys = (u64*)(bnr + 512);                      // 133,200 u64
  // total ws use ~75 MB

  k_split_w<<<dim3(1280), 256, 0, stream>>>(mdw, clsw, clsb, offw, offb, WfA, hwp, hb);
  k_split_f<<<dim3(1640), 256, 0, stream>>>(feat, Fph, Fpl);
  k_conv3_mfma<<<dim3(464), 512, 0, stream>>>(Fph, Fpl, WfA, mdb, out0);
  k_bnstats<<<dim3(512), 256, 0, stream>>>(out0, bnm, bnr);
  k_heads<<<dim3(232), 256, 0, stream>>>(out0, hwp, hb, bnm, bnr, gamma, beta, dout, keys);
  k_post<<<dim3(8), 1024, 0, stream>>>(keys, dout);
}

// Round 14
// 389.164 us; speedup vs baseline: 1.0415x; 1.0415x over previous
//
#include <hip/hip_runtime.h>
#include <cstdint>

// Geometry: B=8, C=512, H=37, W=50, HW=1850, BHW=14800, anchors A=16650, K1=400
#define BHW_ 14800
#define CHW_ 947200
#define A_   16650
#define OCLS 532800
#define OBOX 799200
#define OKEEP 812000
#define NSTEP 144     // 16 cc-chunks * 9 khw

typedef unsigned int u32;
typedef unsigned long long u64;
typedef _Float16 f16x8 __attribute__((ext_vector_type(8)));
typedef float f32x4 __attribute__((ext_vector_type(4)));

union U8 { f16x8 v; u32 u[4]; };
union H2U { _Float16 f; unsigned short u; };

__device__ __forceinline__ unsigned int fkey(float f){
  unsigned int u = __float_as_uint(f);
  return (u & 0x80000000u) ? ~u : (u | 0x80000000u);
}

// anchors exactly as numpy: w=(16*s)/sqrt(r), h=(16*s)*sqrt(r), f64 then f32 cast
__device__ __forceinline__ void anchor_corners(int x, int y, int kk,
                                               float& ax1, float& ay1, float& ax2, float& ay2){
  int si = kk % 3, ri = kk / 3;
  double rv = (ri==0) ? 0.5 : ((ri==1) ? 1.0 : 2.0);
  double sr = sqrt(rv);
  double fs = 128.0 * (double)(si+1);
  double h = fs * sr, w = fs / sr;
  double cx = (double)(x*16 + 8), cy = (double)(y*16 + 8);
  ax1 = (float)(cx - w*0.5); ay1 = (float)(cy - h*0.5);
  ax2 = (float)(cx + w*0.5); ay2 = (float)(cy + h*0.5);
}

// --- merged prepass:
//  [0,8112)      feature -> packed u32 planes Fp[bc][2028], u32 = (lo16<<16)|hi16; pad = 0
//  [8112,9264)   weight-split, coalesced khw-fastest mapping (r10)
//  [9264,9392)   head-pack
__global__ __launch_bounds__(256) void k_prep(const float* __restrict__ feat, const float* __restrict__ mdw,
                                              const float* __restrict__ cw, const float* __restrict__ cb,
                                              const float* __restrict__ ow, const float* __restrict__ ob,
                                              u32* __restrict__ Fp, _Float16* __restrict__ WfA,
                                              float* __restrict__ hwp, float* __restrict__ hb){
  int bid = blockIdx.x;
  if (bid < 8112){
    int q = bid*256 + threadIdx.x;          // < 8*512*507
    int p4 = (q % 507)*4;
    int bc = q / 507;
    u32 outw[4];
    #pragma unroll
    for (int e = 0; e < 4; ++e){
      int padpos = p4 + e;
      int yp = padpos/52, xp = padpos - yp*52;
      float v = 0.f;
      int y = yp - 1, x = xp - 1;
      if ((unsigned)y < 37u && (unsigned)x < 50u) v = feat[(size_t)bc*1850 + y*50 + x];
      _Float16 h = (_Float16)v;
      _Float16 l = (_Float16)(v - (float)h);
      H2U hu, lu; hu.f = h; lu.f = l;
      outw[e] = ((u32)lu.u << 16) | (u32)hu.u;
    }
    *(uint4*)&Fp[(size_t)bc*2028 + p4] = *(uint4*)outw;
  } else if (bid < 9264){
    int u = (bid - 8112)*256 + threadIdx.x; // < 294912 = 16*4*4*128*9
    int khw = u % 9;
    int v = u / 9;                          // < 32768
    int o7  = v & 127;
    int l4g = (v >> 7) & 3;
    int ot  = (v >> 9) & 3;
    int cc  = v >> 11;                      // 0..15
    int o = ot*128 + o7;
    int s = cc*9 + khw;
    f16x8 hi, lo;
    #pragma unroll
    for (int j = 0; j < 8; ++j){
      float val = mdw[(size_t)(o*512 + cc*32 + l4g*8 + j)*9 + khw];
      _Float16 h = (_Float16)val;
      hi[j] = h; lo[j] = (_Float16)(val - (float)h);
    }
    size_t base = ((size_t)(s*4 + ot)*1024 + (size_t)(l4g*2)*128 + o7)*8;
    *(f16x8*)&WfA[base] = hi;
    *(f16x8*)&WfA[base + 1024] = lo;        // +128 chunks (hl=1)
  } else {
    int t = (bid - 9264)*256 + threadIdx.x; // < 32768
    if (t < 64) hb[t] = (t < 18) ? cb[t] : (t < 54 ? ob[t-18] : 0.f);
    int r = t & 63, ci = t >> 6;
    hwp[t] = (r < 18) ? cw[r*512 + ci] : (r < 54 ? ow[(r-18)*512 + ci] : 0.f);
  }
}

// --- 3x3 conv, implicit GEMM, f16x2-split MFMA. 512 threads = 8 waves of 64o x 32n.
// BM=BN=128, BK=32. A: gload_lds staged. B: global->reg early, pack->LDS late (T14).
// One __syncthreads per step; LDS dbuf 64KB -> 2 blocks/CU (~14.5 waves/CU).
// [round 7 kernel verbatim — best measured conv: 232us, MfmaUtil 41%]
__global__ __launch_bounds__(512, 2) void k_conv3_mfma(const u32* __restrict__ Fp,
                                                       const _Float16* __restrict__ WfA,
                                                       const float* __restrict__ mdb,
                                                       float* __restrict__ out0){
  __shared__ _Float16 Abuf[2][8192];
  __shared__ _Float16 Bbuf[2][8192];
  const int tid = threadIdx.x;
  // otile-major XCD grouping: each XCD's blocks share one otile's A slab (2.36MB, L2-fits)
  int flat = blockIdx.x;
  int xcd = flat & 7, sub = flat >> 3;
  int swz = xcd * 58 + sub;
  int otile = swz / 116;
  int ntile = swz - otile*116;

  // B staging role: pos = tid&127, k-octet group kg8 = tid>>7 (0..3)
  const int bpos = tid & 127, kg8 = tid >> 7;
  int n = ntile*128 + bpos; if (n >= BHW_) n = BHW_ - 1;
  int nb = n/1850; int rem = n - nb*1850; int ny = rem/50; int nx = rem - ny*50;
  const u32* bbase = Fp + (size_t)(nb*512 + kg8*8)*2028 + (ny+1)*52 + (nx+1);

  u32 R[8];
  auto loadB = [&](int s){
    int cc = s/9, khw = s - cc*9;
    int dy = khw/3 - 1, dx = khw - (khw/3)*3 - 1;
    const u32* src = bbase + (size_t)cc*32*2028 + dy*52 + dx;
    #pragma unroll
    for (int i = 0; i < 8; ++i) R[i] = src[(size_t)i*2028];
  };
  auto writeB = [&](int cur){
    U8 hi, lo;
    #pragma unroll
    for (int p = 0; p < 4; ++p){
      u32 P0 = R[2*p], P1 = R[2*p+1];
      hi.u[p] = (P1 << 16) | (P0 & 0xFFFFu);
      lo.u[p] = (P0 >> 16) | (P1 & 0xFFFF0000u);
    }
    *(f16x8*)&Bbuf[cur][(size_t)((kg8*2 + 0)*128 + bpos)*8] = hi.v;
    *(f16x8*)&Bbuf[cur][(size_t)((kg8*2 + 1)*128 + bpos)*8] = lo.v;
  };
  auto stageA = [&](int s, int cur){
    const _Float16* g = WfA + ((size_t)(s*4 + otile)*1024 + tid)*8;
    _Float16* l = &Abuf[cur][(size_t)tid*8];
    __builtin_amdgcn_global_load_lds((const __attribute__((address_space(1))) void*)g,
                                     (__attribute__((address_space(3))) void*)l, 16, 0, 0);
    __builtin_amdgcn_global_load_lds((const __attribute__((address_space(1))) void*)(g + 4096),
                                     (__attribute__((address_space(3))) void*)(l + 4096), 16, 0, 0);
  };

  // compute role: 8 waves -> wm = w>>2 (o-half), wn = w&3 (n-quarter)
  const int w = tid >> 6, lane = tid & 63;
  const int wm = w >> 2, wn = w & 3;
  const int l15 = lane & 15, l4 = lane >> 4;

  f32x4 acc[4][2] = {};

  auto compute = [&](int cur){
    f16x8 ah[4], al[4], bh[2], bl[2];
    #pragma unroll
    for (int mf = 0; mf < 4; ++mf){
      int m = wm*64 + mf*16 + l15;
      ah[mf] = *(const f16x8*)&Abuf[cur][(size_t)((l4*2 + 0)*128 + m)*8];
      al[mf] = *(const f16x8*)&Abuf[cur][(size_t)((l4*2 + 1)*128 + m)*8];
    }
    #pragma unroll
    for (int nf = 0; nf < 2; ++nf){
      int nn = wn*32 + nf*16 + l15;
      bh[nf] = *(const f16x8*)&Bbuf[cur][(size_t)((l4*2 + 0)*128 + nn)*8];
      bl[nf] = *(const f16x8*)&Bbuf[cur][(size_t)((l4*2 + 1)*128 + nn)*8];
    }
    #pragma unroll
    for (int mf = 0; mf < 4; ++mf)
      #pragma unroll
      for (int nf = 0; nf < 2; ++nf){
        acc[mf][nf] = __builtin_amdgcn_mfma_f32_16x16x32_f16(ah[mf], bh[nf], acc[mf][nf], 0,0,0);
        acc[mf][nf] = __builtin_amdgcn_mfma_f32_16x16x32_f16(ah[mf], bl[nf], acc[mf][nf], 0,0,0);
        acc[mf][nf] = __builtin_amdgcn_mfma_f32_16x16x32_f16(al[mf], bh[nf], acc[mf][nf], 0,0,0);
      }
  };

  // prologue
  loadB(0);
  stageA(0, 0);
  writeB(0);                 // waits on R; gload_lds drained by the barrier
  __syncthreads();

  int cur = 0;
  for (int s = 0; s < NSTEP; ++s){
    if (s + 1 < NSTEP){
      loadB(s+1);            // issue early: global->reg, consumed after compute
      stageA(s+1, cur^1);    // async -> other buffer
      __builtin_amdgcn_sched_barrier(0);
    }
    compute(cur);
    if (s + 1 < NSTEP) writeB(cur^1);
    __syncthreads();
    cur ^= 1;
  }

  // epilogue: D row = l4*4 + r, col = l15 within each 16x16 frag
  #pragma unroll
  for (int nf = 0; nf < 2; ++nf){
    int ng = ntile*128 + wn*32 + nf*16 + l15;
    if (ng >= BHW_) continue;
    int b2 = ng/1850; int rem2 = ng - b2*1850;
    #pragma unroll
    for (int mf = 0; mf < 4; ++mf){
      int o0 = otile*128 + wm*64 + mf*16 + l4*4;
      #pragma unroll
      for (int r = 0; r < 4; ++r){
        out0[(size_t)b2*CHW_ + (size_t)(o0 + r)*1850 + rem2] = acc[mf][nf][r] + mdb[o0 + r];
      }
    }
  }
}

// --- BN stats per channel (double accumulation)
__global__ __launch_bounds__(256) void k_bnstats(const float* __restrict__ out0,
                                                 float* __restrict__ bnm, float* __restrict__ bnr){
  __shared__ double s1[256], s2[256];
  int c = blockIdx.x, tid = threadIdx.x;
  double a = 0.0, b = 0.0;
  for (int i = tid; i < BHW_; i += 256){
    int bb = i / 1850; int r = i - bb*1850;
    float v = out0[(size_t)bb*CHW_ + (size_t)c*1850 + r];
    a += (double)v; b += (double)v*(double)v;
  }
  s1[tid] = a; s2[tid] = b; __syncthreads();
  for (int off = 128; off; off >>= 1){
    if (tid < off){ s1[tid] += s1[tid+off]; s2[tid] += s2[tid+off]; }
    __syncthreads();
  }
  if (tid == 0){
    double m = s1[0] / 14800.0;
    double var = s2[0] / 14800.0 - m*m;
    bnm[c] = (float)m;
    bnr[c] = 1.0f / sqrtf((float)var + 1e-5f);
  }
}

// --- head GEMM with fused BN+ReLU staging and fused score-key emission
__global__ __launch_bounds__(256) void k_heads(const float* __restrict__ out0, const float* __restrict__ hwp,
                                               const float* __restrict__ hb, const float* __restrict__ bnm,
                                               const float* __restrict__ bnr, const float* __restrict__ gamma,
                                               const float* __restrict__ beta, float* __restrict__ dout,
                                               u64* __restrict__ keys){
#pragma clang fp contract(off)
  __shared__ float As[16][64];
  __shared__ float Bs[16][64];
  __shared__ int sb[64], sy[64], sx[64];
  int tid = threadIdx.x; int ntile = blockIdx.x;
  if (tid < 64){
    int n = ntile*64 + tid;
    if (n < BHW_){ int b = n/1850; int r = n - b*1850; int y = r/50; sb[tid]=b; sy[tid]=y; sx[tid]=r - y*50; }
    else { sb[tid] = -1; sy[tid] = 0; sx[tid] = 0; }
  }
  __syncthreads();
  float acc[4][4] = {};
  const int tx = tid & 15, ty = tid >> 4;
  const int lci = tid >> 4, lo4 = (tid & 15) * 4;
  for (int ct = 0; ct < 32; ++ct){
    int cib = ct*16;
    float4 av = *(const float4*)(hwp + (cib + lci)*64 + lo4);
    float4 bv; float* bp = (float*)&bv;
    int cig = cib + lci;
    float gm = gamma[cig], mm = bnm[cig], rr = bnr[cig], bt = beta[cig];
    #pragma unroll
    for (int j = 0; j < 4; ++j){
      int nn = lo4 + j; int b = sb[nn];
      float v = 0.f;
      if (b >= 0){
        float x = out0[(size_t)b*CHW_ + (size_t)cig*1850 + sy[nn]*50 + sx[nn]];
        float y = gm * (x - mm);
        y = y * rr;
        y = y + bt;
        v = fmaxf(y, 0.f);
      }
      bp[j] = v;
    }
    __syncthreads();
    *(float4*)&As[lci][lo4] = av;
    *(float4*)&Bs[lci][lo4] = bv;
    __syncthreads();
    #pragma unroll
    for (int k = 0; k < 16; ++k){
      float4 a4 = *(const float4*)&As[k][ty*4];
      float4 b4 = *(const float4*)&Bs[k][tx*4];
      const float* ap = (const float*)&a4; const float* bq = (const float*)&b4;
      #pragma unroll
      for (int i = 0; i < 4; ++i)
        #pragma unroll
        for (int j = 0; j < 4; ++j)
          acc[i][j] = fmaf(ap[i], bq[j], acc[i][j]);
    }
  }
  #pragma unroll
  for (int i = 0; i < 4; ++i){
    int r = ty*4 + i;
    if (r >= 54) continue;
    float bias = hb[r];
    #pragma unroll
    for (int j = 0; j < 4; ++j){
      int nl = tx*4 + j;
      int b = sb[nl];
      if (b < 0) continue;
      int pos = sy[nl]*50 + sx[nl];
      float v = acc[i][j] + bias;
      if (r < 18){
        int kk = r >> 1, cc = r & 1;
        dout[OCLS + ((size_t)b*A_ + pos*9 + kk)*2 + cc] = v;
      } else {
        int r2 = r - 18, kk = r2 >> 2, cc = r2 & 3;
        dout[((size_t)b*A_ + pos*9 + kk)*4 + cc] = v;
      }
    }
  }
  if (ty < 5){
    #pragma unroll
    for (int i = 0; i < 4; i += 2){
      int r = ty*4 + i;
      if (r >= 18) continue;
      int kk = r >> 1;
      float b0 = hb[r], b1 = hb[r+1];
      #pragma unroll
      for (int j = 0; j < 4; ++j){
        int nl = tx*4 + j;
        int b = sb[nl];
        if (b < 0) continue;
        float c0 = acc[i][j] + b0;
        float c1 = acc[i+1][j] + b1;
        float d = c1 - c0;
        float ax1, ay1, ax2, ay2;
        anchor_corners(sx[nl], sy[nl], kk, ax1, ay1, ax2, ay2);
        bool valid = (ax1 >= 0.f) && (ay1 >= 0.f) && (ax2 < 800.f) && (ay2 < 592.f);
        unsigned a = (unsigned)(sy[nl]*50 + sx[nl])*9u + (unsigned)kk;
        u64 key = valid ? (((u64)fkey(d) << 32) | (u64)(~a)) : 0ull;
        keys[(size_t)b*A_ + a] = key;
      }
    }
  }
}

// --- fused deterministic post: 2-level histogram threshold -> LDS compact -> LDS rank
//     -> decode -> adjacency NMS. NO intra-kernel global scratch (r8 lesson).
__global__ __launch_bounds__(1024) void k_post(const u64* __restrict__ keys,
                                               float* __restrict__ dout){
#pragma clang fp contract(off)
  __shared__ u32 hist[4096];
  __shared__ u32 sp[1024];
  __shared__ u64 selbuf[4096];
  __shared__ u64 stopk[400];
  __shared__ u32 adj32[6400];
  __shared__ float X1[400], Y1[400], X2[400], Y2[400], AR[400];
  __shared__ u32 ssup[13];
  __shared__ u32 s_t1, s_base1, s_t2, scnt;
  int b = blockIdx.x, tid = threadIdx.x;
  const u64* kb = keys + (size_t)b*A_;

  // ---- pass 1: histogram of key bits [52,63] over nonzero keys
  for (int i = tid; i < 4096; i += 1024) hist[i] = 0u;
  if (tid == 0) scnt = 0u;
  __syncthreads();
  for (int i = tid; i < A_; i += 1024){
    u64 k = kb[i];
    if (k) atomicAdd(&hist[(u32)(k >> 52)], 1u);
  }
  __syncthreads();
  {
    u32 p = hist[tid*4] + hist[tid*4+1] + hist[tid*4+2] + hist[tid*4+3];
    sp[tid] = p; __syncthreads();
    for (int off = 1; off < 1024; off <<= 1){
      u32 v = sp[tid] + ((tid + off < 1024) ? sp[tid + off] : 0u);
      __syncthreads(); sp[tid] = v; __syncthreads();
    }
    if (sp[tid] >= 400u && (tid == 1023 || sp[tid+1] < 400u)){
      u32 cum = (tid == 1023) ? 0u : sp[tid+1];
      for (int bb = tid*4 + 3; bb >= tid*4; --bb){
        cum += hist[bb];
        if (cum >= 400u){ s_t1 = (u32)bb; s_base1 = cum - hist[bb]; break; }
      }
    }
  }
  __syncthreads();
  const u32 t1 = s_t1;
  const u32 need2 = 400u - s_base1;   // >= 1

  // ---- pass 2: histogram of bits [40,51] among keys whose top-12 == t1
  __syncthreads();
  for (int i = tid; i < 4096; i += 1024) hist[i] = 0u;
  __syncthreads();
  for (int i = tid; i < A_; i += 1024){
    u64 k = kb[i];
    if (k && (u32)(k >> 52) == t1) atomicAdd(&hist[(u32)(k >> 40) & 0xFFFu], 1u);
  }
  __syncthreads();
  {
    u32 p = hist[tid*4] + hist[tid*4+1] + hist[tid*4+2] + hist[tid*4+3];
    sp[tid] = p; __syncthreads();
    for (int off = 1; off < 1024; off <<= 1){
      u32 v = sp[tid] + ((tid + off < 1024) ? sp[tid + off] : 0u);
      __syncthreads(); sp[tid] = v; __syncthreads();
    }
    if (sp[tid] >= need2 && (tid == 1023 || sp[tid+1] < need2)){
      u32 cum = (tid == 1023) ? 0u : sp[tid+1];
      for (int bb = tid*4 + 3; bb >= tid*4; --bb){
        cum += hist[bb];
        if (cum >= need2){ s_t2 = (u32)bb; break; }
      }
    }
  }
  __syncthreads();
  const u32 t2 = s_t2;

  // ---- compact selected keys into LDS (order nondeterministic; rank fixes it)
  for (int i = tid; i < A_; i += 1024){
    u64 k = kb[i];
    if (!k) continue;
    u32 top = (u32)(k >> 52);
    bool sel = (top > t1) || (top == t1 && ((u32)(k >> 40) & 0xFFFu) >= t2);
    if (sel){
      u32 pidx = atomicAdd(&scnt, 1u);
      if (pidx < 4096u) selbuf[pidx] = k;
    }
  }
  __syncthreads();
  int C = min((int)scnt, 4096);

  // ---- exact in-LDS rank-by-counting -> ordered top-400
  for (int i = tid; i < C; i += 1024){
    u64 my = selbuf[i];
    int c = 0;
    for (int j = 0; j < C; ++j) c += (selbuf[j] > my) ? 1 : 0;
    if (c < 400) stopk[c] = my;
  }
  __syncthreads();

  // ---- decode boxes + adjacency bitmask
  for (int i = tid; i < 6400; i += 1024) adj32[i] = 0u;
  if (tid < 400){
    u64 key = stopk[tid];
    unsigned a = ~(unsigned)(key & 0xFFFFFFFFull);
    int pos = a/9; int kk = a - pos*9;
    int y = pos/50; int x = pos - y*50;
    float ax1, ay1, ax2, ay2;
    anchor_corners(x, y, kk, ax1, ay1, ax2, ay2);
    float xa = (ax1 + ax2) * 0.5f;
    float ya = (ay1 + ay2) * 0.5f;
    float wa = ax2 - ax1 + 1.0f;
    float ha = ay2 - ay1 + 1.0f;
    const float* t = dout + ((size_t)b*A_ + a)*4;
    float t0 = t[0], t1f = t[1], t2f = t[2], t3 = t[3];
    float xc = t0 * wa + xa;
    float yc = t1f * ha + ya;
    float bw = wa * expf(t2f);
    float bh = ha * expf(t3);
    float bx1 = xc - bw*0.5f, by1 = yc - bh*0.5f;
    float bx2 = xc + bw*0.5f, by2 = yc + bh*0.5f;
    float* bo = dout + OBOX + ((size_t)b*400 + tid)*4;
    bo[0] = bx1; bo[1] = by1; bo[2] = bx2; bo[3] = by2;
    float tx1 = truncf(bx1), ty1 = truncf(by1), tx2 = truncf(bx2), ty2 = truncf(by2);
    X1[tid] = tx1; Y1[tid] = ty1; X2[tid] = tx2; Y2[tid] = ty2;
    AR[tid] = (tx2 - tx1 + 1.0f) * (ty2 - ty1 + 1.0f);
  }
  __syncthreads();
  for (int q = tid; q < 160000; q += 1024){
    int i = q / 400, j = q - i*400;
    if (j > i){
      float iw = fminf(X2[i], X2[j]) - fmaxf(X1[i], X1[j]) + 1.0f; iw = fmaxf(iw, 0.f);
      float ih = fminf(Y2[i], Y2[j]) - fmaxf(Y1[i], Y1[j]) + 1.0f; ih = fmaxf(ih, 0.f);
      float inter = iw * ih;
      float iou = inter / ((AR[i] + AR[j]) - inter);
      if (iou > 0.6f) atomicOr(&adj32[i*16 + (j >> 5)], 1u << (j & 31));
    }
  }
  __syncthreads();
  // ---- serial greedy over the adjacency bitmask (wave 0, lockstep)
  if (tid < 64){
    u32 sup = 0;
    for (int i = 0; i < 399; ++i){
      u32 a = (tid < 13) ? adj32[i*16 + tid] : 0u;
      u32 so = __shfl(sup, i >> 5);
      if (!((so >> (i & 31)) & 1u)) sup |= a;
    }
    if (tid < 13) ssup[tid] = sup;
  }
  __syncthreads();
  if (tid < 400)
    dout[OKEEP + (size_t)b*400 + tid] = ((ssup[tid >> 5] >> (tid & 31)) & 1u) ? 0.f : 1.f;
}

extern "C" void kernel_launch(void* const* d_in, const int* in_sizes, int n_in,
                              void* d_out, int out_size, void* d_ws, size_t ws_size,
                              hipStream_t stream){
  const float* feat  = (const float*)d_in[0];
  const float* mdw   = (const float*)d_in[1];
  const float* mdb   = (const float*)d_in[2];
  const float* gamma = (const float*)d_in[3];
  const float* beta  = (const float*)d_in[4];
  const float* clsw  = (const float*)d_in[5];
  const float* clsb  = (const float*)d_in[6];
  const float* offw  = (const float*)d_in[7];
  const float* offb  = (const float*)d_in[8];
  float* dout = (float*)d_out;
  float* ws = (float*)d_ws;

  float* out0 = ws;                                   // 7,577,600 f32
  _Float16* WfA = (_Float16*)(out0 + 7577600);        // 4,718,592 f16 (2,359,296 f32)
  u32* Fp = (u32*)(out0 + 7577600 + 2359296);         // 8,306,688 u32
  float* hwp = (float*)(Fp + 8306688);                // 32,768
  float* hb  = hwp + 32768;                           // 64
  float* bnm = hb + 64;                               // 512
  float* bnr = bnm + 512;                             // 512
  u64* keys = (u64*)(bnr + 512);                      // 133,200 u64
  // total ws use ~75 MB

  k_prep<<<dim3(9392), 256, 0, stream>>>(feat, mdw, clsw, clsb, offw, offb, Fp, WfA, hwp, hb);
  k_conv3_mfma<<<dim3(464), 512, 0, stream>>>(Fp, WfA, mdb, out0);
  k_bnstats<<<dim3(512), 256, 0, stream>>>(out0, bnm, bnr);
  k_heads<<<dim3(232), 256, 0, stream>>>(out0, hwp, hb, bnm, bnr, gamma, beta, dout, keys);
  k_post<<<dim3(8), 1024, 0, stream>>>(keys, dout);
}

// Round 15
// 381.983 us; speedup vs baseline: 1.0611x; 1.0188x over previous
//
#include <hip/hip_runtime.h>
#include <cstdint>

// Geometry: B=8, C=512, H=37, W=50, HW=1850, BHW=14800, anchors A=16650, K1=400
#define BHW_ 14800
#define CHW_ 947200
#define A_   16650
#define OCLS 532800
#define OBOX 799200
#define OKEEP 812000
#define NSTEP 144     // 16 cc-chunks * 9 khw

typedef unsigned int u32;
typedef unsigned long long u64;
typedef _Float16 f16x8 __attribute__((ext_vector_type(8)));
typedef float f32x4 __attribute__((ext_vector_type(4)));

union U8 { f16x8 v; u32 u[4]; };
union H2U { _Float16 f; unsigned short u; };

__device__ __forceinline__ unsigned int fkey(float f){
  unsigned int u = __float_as_uint(f);
  return (u & 0x80000000u) ? ~u : (u | 0x80000000u);
}

// anchors exactly as numpy: w=(16*s)/sqrt(r), h=(16*s)*sqrt(r), f64 then f32 cast
__device__ __forceinline__ void anchor_corners(int x, int y, int kk,
                                               float& ax1, float& ay1, float& ax2, float& ay2){
  int si = kk % 3, ri = kk / 3;
  double rv = (ri==0) ? 0.5 : ((ri==1) ? 1.0 : 2.0);
  double sr = sqrt(rv);
  double fs = 128.0 * (double)(si+1);
  double h = fs * sr, w = fs / sr;
  double cx = (double)(x*16 + 8), cy = (double)(y*16 + 8);
  ax1 = (float)(cx - w*0.5); ay1 = (float)(cy - h*0.5);
  ax2 = (float)(cx + w*0.5); ay2 = (float)(cy + h*0.5);
}

// --- merged prepass:
//  [0,8112)      feature -> packed u32 planes Fp[bc][2028], u32 = (lo16<<16)|hi16; pad = 0
//  [8112,9264)   weight-split, coalesced khw-fastest mapping
//  [9264,9392)   head-pack + zero BN-stat accumulators
__global__ __launch_bounds__(256) void k_prep(const float* __restrict__ feat, const float* __restrict__ mdw,
                                              const float* __restrict__ cw, const float* __restrict__ cb,
                                              const float* __restrict__ ow, const float* __restrict__ ob,
                                              u32* __restrict__ Fp, _Float16* __restrict__ WfA,
                                              float* __restrict__ hwp, float* __restrict__ hb,
                                              u64* __restrict__ Sg){
  int bid = blockIdx.x;
  if (bid < 8112){
    int q = bid*256 + threadIdx.x;          // < 8*512*507
    int p4 = (q % 507)*4;
    int bc = q / 507;
    u32 outw[4];
    #pragma unroll
    for (int e = 0; e < 4; ++e){
      int padpos = p4 + e;
      int yp = padpos/52, xp = padpos - yp*52;
      float v = 0.f;
      int y = yp - 1, x = xp - 1;
      if ((unsigned)y < 37u && (unsigned)x < 50u) v = feat[(size_t)bc*1850 + y*50 + x];
      _Float16 h = (_Float16)v;
      _Float16 l = (_Float16)(v - (float)h);
      H2U hu, lu; hu.f = h; lu.f = l;
      outw[e] = ((u32)lu.u << 16) | (u32)hu.u;
    }
    *(uint4*)&Fp[(size_t)bc*2028 + p4] = *(uint4*)outw;
  } else if (bid < 9264){
    int u = (bid - 8112)*256 + threadIdx.x; // < 294912 = 16*4*4*128*9
    int khw = u % 9;
    int v = u / 9;                          // < 32768
    int o7  = v & 127;
    int l4g = (v >> 7) & 3;
    int ot  = (v >> 9) & 3;
    int cc  = v >> 11;                      // 0..15
    int o = ot*128 + o7;
    int s = cc*9 + khw;
    f16x8 hi, lo;
    #pragma unroll
    for (int j = 0; j < 8; ++j){
      float val = mdw[(size_t)(o*512 + cc*32 + l4g*8 + j)*9 + khw];
      _Float16 h = (_Float16)val;
      hi[j] = h; lo[j] = (_Float16)(val - (float)h);
    }
    size_t base = ((size_t)(s*4 + ot)*1024 + (size_t)(l4g*2)*128 + o7)*8;
    *(f16x8*)&WfA[base] = hi;
    *(f16x8*)&WfA[base + 1024] = lo;        // +128 chunks (hl=1)
  } else {
    int t = (bid - 9264)*256 + threadIdx.x; // < 32768
    if (t < 64) hb[t] = (t < 18) ? cb[t] : (t < 54 ? ob[t-18] : 0.f);
    if (t < 1024) Sg[t] = 0ull;             // zero BN-stat accumulators every call
    int r = t & 63, ci = t >> 6;
    hwp[t] = (r < 18) ? cw[r*512 + ci] : (r < 54 ? ow[(r-18)*512 + ci] : 0.f);
  }
}

// --- 3x3 conv, implicit GEMM, f16x2-split MFMA. 512 threads = 8 waves of 64o x 32n.
// BM=BN=128, BK=32. A: gload_lds staged. B: global->reg early, pack->LDS late (T14).
// One __syncthreads per step; LDS dbuf 64KB -> 2 blocks/CU. [r7 conv, best measured: 232us]
// NEW: BN stats accumulated in the epilogue via deterministic fixed-point i64 atomics
// (integer adds are associative -> bit-identical across replays regardless of order).
__global__ __launch_bounds__(512, 2) void k_conv3_mfma(const u32* __restrict__ Fp,
                                                       const _Float16* __restrict__ WfA,
                                                       const float* __restrict__ mdb,
                                                       float* __restrict__ out0,
                                                       u64* __restrict__ Sg){
  __shared__ _Float16 Abuf[2][8192];
  __shared__ _Float16 Bbuf[2][8192];
  __shared__ u64 Sred[256];   // [128 ch][2: sum, sumsq]
  const int tid = threadIdx.x;
  if (tid < 256) Sred[tid] = 0ull;
  // otile-major XCD grouping: each XCD's blocks share one otile's A slab (2.36MB, L2-fits)
  int flat = blockIdx.x;
  int xcd = flat & 7, sub = flat >> 3;
  int swz = xcd * 58 + sub;
  int otile = swz / 116;
  int ntile = swz - otile*116;

  // B staging role: pos = tid&127, k-octet group kg8 = tid>>7 (0..3)
  const int bpos = tid & 127, kg8 = tid >> 7;
  int n = ntile*128 + bpos; if (n >= BHW_) n = BHW_ - 1;
  int nb = n/1850; int rem = n - nb*1850; int ny = rem/50; int nx = rem - ny*50;
  const u32* bbase = Fp + (size_t)(nb*512 + kg8*8)*2028 + (ny+1)*52 + (nx+1);

  u32 R[8];
  auto loadB = [&](int s){
    int cc = s/9, khw = s - cc*9;
    int dy = khw/3 - 1, dx = khw - (khw/3)*3 - 1;
    const u32* src = bbase + (size_t)cc*32*2028 + dy*52 + dx;
    #pragma unroll
    for (int i = 0; i < 8; ++i) R[i] = src[(size_t)i*2028];
  };
  auto writeB = [&](int cur){
    U8 hi, lo;
    #pragma unroll
    for (int p = 0; p < 4; ++p){
      u32 P0 = R[2*p], P1 = R[2*p+1];
      hi.u[p] = (P1 << 16) | (P0 & 0xFFFFu);
      lo.u[p] = (P0 >> 16) | (P1 & 0xFFFF0000u);
    }
    *(f16x8*)&Bbuf[cur][(size_t)((kg8*2 + 0)*128 + bpos)*8] = hi.v;
    *(f16x8*)&Bbuf[cur][(size_t)((kg8*2 + 1)*128 + bpos)*8] = lo.v;
  };
  auto stageA = [&](int s, int cur){
    const _Float16* g = WfA + ((size_t)(s*4 + otile)*1024 + tid)*8;
    _Float16* l = &Abuf[cur][(size_t)tid*8];
    __builtin_amdgcn_global_load_lds((const __attribute__((address_space(1))) void*)g,
                                     (__attribute__((address_space(3))) void*)l, 16, 0, 0);
    __builtin_amdgcn_global_load_lds((const __attribute__((address_space(1))) void*)(g + 4096),
                                     (__attribute__((address_space(3))) void*)(l + 4096), 16, 0, 0);
  };

  // compute role: 8 waves -> wm = w>>2 (o-half), wn = w&3 (n-quarter)
  const int w = tid >> 6, lane = tid & 63;
  const int wm = w >> 2, wn = w & 3;
  const int l15 = lane & 15, l4 = lane >> 4;

  f32x4 acc[4][2] = {};

  auto compute = [&](int cur){
    f16x8 ah[4], al[4], bh[2], bl[2];
    #pragma unroll
    for (int mf = 0; mf < 4; ++mf){
      int m = wm*64 + mf*16 + l15;
      ah[mf] = *(const f16x8*)&Abuf[cur][(size_t)((l4*2 + 0)*128 + m)*8];
      al[mf] = *(const f16x8*)&Abuf[cur][(size_t)((l4*2 + 1)*128 + m)*8];
    }
    #pragma unroll
    for (int nf = 0; nf < 2; ++nf){
      int nn = wn*32 + nf*16 + l15;
      bh[nf] = *(const f16x8*)&Bbuf[cur][(size_t)((l4*2 + 0)*128 + nn)*8];
      bl[nf] = *(const f16x8*)&Bbuf[cur][(size_t)((l4*2 + 1)*128 + nn)*8];
    }
    #pragma unroll
    for (int mf = 0; mf < 4; ++mf)
      #pragma unroll
      for (int nf = 0; nf < 2; ++nf){
        acc[mf][nf] = __builtin_amdgcn_mfma_f32_16x16x32_f16(ah[mf], bh[nf], acc[mf][nf], 0,0,0);
        acc[mf][nf] = __builtin_amdgcn_mfma_f32_16x16x32_f16(ah[mf], bl[nf], acc[mf][nf], 0,0,0);
        acc[mf][nf] = __builtin_amdgcn_mfma_f32_16x16x32_f16(al[mf], bh[nf], acc[mf][nf], 0,0,0);
      }
  };

  // prologue
  loadB(0);
  stageA(0, 0);
  writeB(0);                 // waits on R; gload_lds drained by the barrier
  __syncthreads();

  int cur = 0;
  for (int s = 0; s < NSTEP; ++s){
    if (s + 1 < NSTEP){
      loadB(s+1);            // issue early: global->reg, consumed after compute
      stageA(s+1, cur^1);    // async -> other buffer
      __builtin_amdgcn_sched_barrier(0);
    }
    compute(cur);
    if (s + 1 < NSTEP) writeB(cur^1);
    __syncthreads();
    cur ^= 1;
  }

  // epilogue: store C and accumulate BN stats.
  // D row = l4*4 + r, col = l15 within each 16x16 frag.
  #pragma unroll
  for (int nf = 0; nf < 2; ++nf){
    int ng = ntile*128 + wn*32 + nf*16 + l15;
    if (ng >= BHW_) continue;
    int b2 = ng/1850; int rem2 = ng - b2*1850;
    #pragma unroll
    for (int mf = 0; mf < 4; ++mf){
      int o0 = otile*128 + wm*64 + mf*16 + l4*4;
      #pragma unroll
      for (int r = 0; r < 4; ++r){
        out0[(size_t)b2*CHW_ + (size_t)(o0 + r)*1850 + rem2] = acc[mf][nf][r] + mdb[o0 + r];
      }
    }
  }
  // BN stats: per (mf,r) channel, sum v and v^2 in fixed point (v*2^24, v^2*2^30; v^2 exact in double)
  #pragma unroll
  for (int mf = 0; mf < 4; ++mf){
    int o0 = otile*128 + wm*64 + mf*16 + l4*4;
    #pragma unroll
    for (int r = 0; r < 4; ++r){
      float bias = mdb[o0 + r];
      long long s = 0, s2 = 0;
      #pragma unroll
      for (int nf = 0; nf < 2; ++nf){
        int ng = ntile*128 + wn*32 + nf*16 + l15;
        if (ng < BHW_){
          double v = (double)(acc[mf][nf][r] + bias);
          s  += __double2ll_rn(v * 16777216.0);
          s2 += __double2ll_rn(v * v * 1073741824.0);
        }
      }
      // reduce over the 16 position-lanes (lane = l4*16 + l15; xor of low 4 bits stays in-group)
      #pragma unroll
      for (int m2 = 1; m2 < 16; m2 <<= 1){
        s  += __shfl_xor(s,  m2, 64);
        s2 += __shfl_xor(s2, m2, 64);
      }
      if (l15 == 0){
        int cloc = wm*64 + mf*16 + l4*4 + r;
        atomicAdd(&Sred[cloc*2],   (u64)s);
        atomicAdd(&Sred[cloc*2+1], (u64)s2);
      }
    }
  }
  __syncthreads();
  if (tid < 256) atomicAdd(&Sg[otile*256 + tid], Sred[tid]);
}

// --- head GEMM with fused BN-stat finalize + BN+ReLU staging + score-key emission
__global__ __launch_bounds__(256) void k_heads(const float* __restrict__ out0, const float* __restrict__ hwp,
                                               const float* __restrict__ hb, const u64* __restrict__ Sg,
                                               const float* __restrict__ gamma,
                                               const float* __restrict__ beta, float* __restrict__ dout,
                                               u64* __restrict__ keys){
#pragma clang fp contract(off)
  __shared__ float As[16][64];
  __shared__ float Bs[16][64];
  __shared__ float bnmL[512], bnrL[512];
  __shared__ int sb[64], sy[64], sx[64];
  int tid = threadIdx.x; int ntile = blockIdx.x;
  // finalize BN stats from fixed-point sums (same formula as the old f64 k_bnstats)
  for (int c = tid; c < 512; c += 256){
    double s  = (double)(long long)Sg[c*2]   / 16777216.0;
    double s2 = (double)(long long)Sg[c*2+1] / 1073741824.0;
    double m = s / 14800.0;
    double var = s2 / 14800.0 - m*m;
    bnmL[c] = (float)m;
    bnrL[c] = 1.0f / sqrtf((float)var + 1e-5f);
  }
  if (tid < 64){
    int n = ntile*64 + tid;
    if (n < BHW_){ int b = n/1850; int r = n - b*1850; int y = r/50; sb[tid]=b; sy[tid]=y; sx[tid]=r - y*50; }
    else { sb[tid] = -1; sy[tid] = 0; sx[tid] = 0; }
  }
  __syncthreads();
  float acc[4][4] = {};
  const int tx = tid & 15, ty = tid >> 4;
  const int lci = tid >> 4, lo4 = (tid & 15) * 4;
  for (int ct = 0; ct < 32; ++ct){
    int cib = ct*16;
    float4 av = *(const float4*)(hwp + (cib + lci)*64 + lo4);
    float4 bv; float* bp = (float*)&bv;
    int cig = cib + lci;
    float gm = gamma[cig], mm = bnmL[cig], rr = bnrL[cig], bt = beta[cig];
    #pragma unroll
    for (int j = 0; j < 4; ++j){
      int nn = lo4 + j; int b = sb[nn];
      float v = 0.f;
      if (b >= 0){
        float x = out0[(size_t)b*CHW_ + (size_t)cig*1850 + sy[nn]*50 + sx[nn]];
        float y = gm * (x - mm);
        y = y * rr;
        y = y + bt;
        v = fmaxf(y, 0.f);
      }
      bp[j] = v;
    }
    __syncthreads();
    *(float4*)&As[lci][lo4] = av;
    *(float4*)&Bs[lci][lo4] = bv;
    __syncthreads();
    #pragma unroll
    for (int k = 0; k < 16; ++k){
      float4 a4 = *(const float4*)&As[k][ty*4];
      float4 b4 = *(const float4*)&Bs[k][tx*4];
      const float* ap = (const float*)&a4; const float* bq = (const float*)&b4;
      #pragma unroll
      for (int i = 0; i < 4; ++i)
        #pragma unroll
        for (int j = 0; j < 4; ++j)
          acc[i][j] = fmaf(ap[i], bq[j], acc[i][j]);
    }
  }
  #pragma unroll
  for (int i = 0; i < 4; ++i){
    int r = ty*4 + i;
    if (r >= 54) continue;
    float bias = hb[r];
    #pragma unroll
    for (int j = 0; j < 4; ++j){
      int nl = tx*4 + j;
      int b = sb[nl];
      if (b < 0) continue;
      int pos = sy[nl]*50 + sx[nl];
      float v = acc[i][j] + bias;
      if (r < 18){
        int kk = r >> 1, cc = r & 1;
        dout[OCLS + ((size_t)b*A_ + pos*9 + kk)*2 + cc] = v;
      } else {
        int r2 = r - 18, kk = r2 >> 2, cc = r2 & 3;
        dout[((size_t)b*A_ + pos*9 + kk)*4 + cc] = v;
      }
    }
  }
  if (ty < 5){
    #pragma unroll
    for (int i = 0; i < 4; i += 2){
      int r = ty*4 + i;
      if (r >= 18) continue;
      int kk = r >> 1;
      float b0 = hb[r], b1 = hb[r+1];
      #pragma unroll
      for (int j = 0; j < 4; ++j){
        int nl = tx*4 + j;
        int b = sb[nl];
        if (b < 0) continue;
        float c0 = acc[i][j] + b0;
        float c1 = acc[i+1][j] + b1;
        float d = c1 - c0;
        float ax1, ay1, ax2, ay2;
        anchor_corners(sx[nl], sy[nl], kk, ax1, ay1, ax2, ay2);
        bool valid = (ax1 >= 0.f) && (ay1 >= 0.f) && (ax2 < 800.f) && (ay2 < 592.f);
        unsigned a = (unsigned)(sy[nl]*50 + sx[nl])*9u + (unsigned)kk;
        u64 key = valid ? (((u64)fkey(d) << 32) | (u64)(~a)) : 0ull;
        keys[(size_t)b*A_ + a] = key;
      }
    }
  }
}

// --- fused deterministic post: 2-level histogram threshold -> LDS compact -> LDS rank
//     -> decode -> adjacency NMS. NO intra-kernel global scratch (r8 lesson).
__global__ __launch_bounds__(1024) void k_post(const u64* __restrict__ keys,
                                               float* __restrict__ dout){
#pragma clang fp contract(off)
  __shared__ u32 hist[4096];
  __shared__ u32 sp[1024];
  __shared__ u64 selbuf[4096];
  __shared__ u64 stopk[400];
  __shared__ u32 adj32[6400];
  __shared__ float X1[400], Y1[400], X2[400], Y2[400], AR[400];
  __shared__ u32 ssup[13];
  __shared__ u32 s_t1, s_base1, s_t2, scnt;
  int b = blockIdx.x, tid = threadIdx.x;
  const u64* kb = keys + (size_t)b*A_;

  // ---- pass 1: histogram of key bits [52,63] over nonzero keys
  for (int i = tid; i < 4096; i += 1024) hist[i] = 0u;
  if (tid == 0) scnt = 0u;
  __syncthreads();
  for (int i = tid; i < A_; i += 1024){
    u64 k = kb[i];
    if (k) atomicAdd(&hist[(u32)(k >> 52)], 1u);
  }
  __syncthreads();
  {
    u32 p = hist[tid*4] + hist[tid*4+1] + hist[tid*4+2] + hist[tid*4+3];
    sp[tid] = p; __syncthreads();
    for (int off = 1; off < 1024; off <<= 1){
      u32 v = sp[tid] + ((tid + off < 1024) ? sp[tid + off] : 0u);
      __syncthreads(); sp[tid] = v; __syncthreads();
    }
    if (sp[tid] >= 400u && (tid == 1023 || sp[tid+1] < 400u)){
      u32 cum = (tid == 1023) ? 0u : sp[tid+1];
      for (int bb = tid*4 + 3; bb >= tid*4; --bb){
        cum += hist[bb];
        if (cum >= 400u){ s_t1 = (u32)bb; s_base1 = cum - hist[bb]; break; }
      }
    }
  }
  __syncthreads();
  const u32 t1 = s_t1;
  const u32 need2 = 400u - s_base1;   // >= 1

  // ---- pass 2: histogram of bits [40,51] among keys whose top-12 == t1
  __syncthreads();
  for (int i = tid; i < 4096; i += 1024) hist[i] = 0u;
  __syncthreads();
  for (int i = tid; i < A_; i += 1024){
    u64 k = kb[i];
    if (k && (u32)(k >> 52) == t1) atomicAdd(&hist[(u32)(k >> 40) & 0xFFFu], 1u);
  }
  __syncthreads();
  {
    u32 p = hist[tid*4] + hist[tid*4+1] + hist[tid*4+2] + hist[tid*4+3];
    sp[tid] = p; __syncthreads();
    for (int off = 1; off < 1024; off <<= 1){
      u32 v = sp[tid] + ((tid + off < 1024) ? sp[tid + off] : 0u);
      __syncthreads(); sp[tid] = v; __syncthreads();
    }
    if (sp[tid] >= need2 && (tid == 1023 || sp[tid+1] < need2)){
      u32 cum = (tid == 1023) ? 0u : sp[tid+1];
      for (int bb = tid*4 + 3; bb >= tid*4; --bb){
        cum += hist[bb];
        if (cum >= need2){ s_t2 = (u32)bb; break; }
      }
    }
  }
  __syncthreads();
  const u32 t2 = s_t2;

  // ---- compact selected keys into LDS (order nondeterministic; rank fixes it)
  for (int i = tid; i < A_; i += 1024){
    u64 k = kb[i];
    if (!k) continue;
    u32 top = (u32)(k >> 52);
    bool sel = (top > t1) || (top == t1 && ((u32)(k >> 40) & 0xFFFu) >= t2);
    if (sel){
      u32 pidx = atomicAdd(&scnt, 1u);
      if (pidx < 4096u) selbuf[pidx] = k;
    }
  }
  __syncthreads();
  int C = min((int)scnt, 4096);

  // ---- exact in-LDS rank-by-counting -> ordered top-400
  for (int i = tid; i < C; i += 1024){
    u64 my = selbuf[i];
    int c = 0;
    for (int j = 0; j < C; ++j) c += (selbuf[j] > my) ? 1 : 0;
    if (c < 400) stopk[c] = my;
  }
  __syncthreads();

  // ---- decode boxes + adjacency bitmask
  for (int i = tid; i < 6400; i += 1024) adj32[i] = 0u;
  if (tid < 400){
    u64 key = stopk[tid];
    unsigned a = ~(unsigned)(key & 0xFFFFFFFFull);
    int pos = a/9; int kk = a - pos*9;
    int y = pos/50; int x = pos - y*50;
    float ax1, ay1, ax2, ay2;
    anchor_corners(x, y, kk, ax1, ay1, ax2, ay2);
    float xa = (ax1 + ax2) * 0.5f;
    float ya = (ay1 + ay2) * 0.5f;
    float wa = ax2 - ax1 + 1.0f;
    float ha = ay2 - ay1 + 1.0f;
    const float* t = dout + ((size_t)b*A_ + a)*4;
    float t0 = t[0], t1f = t[1], t2f = t[2], t3 = t[3];
    float xc = t0 * wa + xa;
    float yc = t1f * ha + ya;
    float bw = wa * expf(t2f);
    float bh = ha * expf(t3);
    float bx1 = xc - bw*0.5f, by1 = yc - bh*0.5f;
    float bx2 = xc + bw*0.5f, by2 = yc + bh*0.5f;
    float* bo = dout + OBOX + ((size_t)b*400 + tid)*4;
    bo[0] = bx1; bo[1] = by1; bo[2] = bx2; bo[3] = by2;
    float tx1 = truncf(bx1), ty1 = truncf(by1), tx2 = truncf(bx2), ty2 = truncf(by2);
    X1[tid] = tx1; Y1[tid] = ty1; X2[tid] = tx2; Y2[tid] = ty2;
    AR[tid] = (tx2 - tx1 + 1.0f) * (ty2 - ty1 + 1.0f);
  }
  __syncthreads();
  for (int q = tid; q < 160000; q += 1024){
    int i = q / 400, j = q - i*400;
    if (j > i){
      float iw = fminf(X2[i], X2[j]) - fmaxf(X1[i], X1[j]) + 1.0f; iw = fmaxf(iw, 0.f);
      float ih = fminf(Y2[i], Y2[j]) - fmaxf(Y1[i], Y1[j]) + 1.0f; ih = fmaxf(ih, 0.f);
      float inter = iw * ih;
      float iou = inter / ((AR[i] + AR[j]) - inter);
      if (iou > 0.6f) atomicOr(&adj32[i*16 + (j >> 5)], 1u << (j & 31));
    }
  }
  __syncthreads();
  // ---- serial greedy over the adjacency bitmask (wave 0, lockstep)
  if (tid < 64){
    u32 sup = 0;
    for (int i = 0; i < 399; ++i){
      u32 a = (tid < 13) ? adj32[i*16 + tid] : 0u;
      u32 so = __shfl(sup, i >> 5);
      if (!((so >> (i & 31)) & 1u)) sup |= a;
    }
    if (tid < 13) ssup[tid] = sup;
  }
  __syncthreads();
  if (tid < 400)
    dout[OKEEP + (size_t)b*400 + tid] = ((ssup[tid >> 5] >> (tid & 31)) & 1u) ? 0.f : 1.f;
}

extern "C" void kernel_launch(void* const* d_in, const int* in_sizes, int n_in,
                              void* d_out, int out_size, void* d_ws, size_t ws_size,
                              hipStream_t stream){
  const float* feat  = (const float*)d_in[0];
  const float* mdw   = (const float*)d_in[1];
  const float* mdb   = (const float*)d_in[2];
  const float* gamma = (const float*)d_in[3];
  const float* beta  = (const float*)d_in[4];
  const float* clsw  = (const float*)d_in[5];
  const float* clsb  = (const float*)d_in[6];
  const float* offw  = (const float*)d_in[7];
  const float* offb  = (const float*)d_in[8];
  float* dout = (float*)d_out;
  float* ws = (float*)d_ws;

  float* out0 = ws;                                   // 7,577,600 f32
  _Float16* WfA = (_Float16*)(out0 + 7577600);        // 4,718,592 f16 (2,359,296 f32)
  u32* Fp = (u32*)(out0 + 7577600 + 2359296);         // 8,306,688 u32
  float* hwp = (float*)(Fp + 8306688);                // 32,768
  float* hb  = hwp + 32768;                           // 64
  u64* Sg = (u64*)(hb + 64);                          // 1024 u64 (8B-aligned: 18,276,416 f32 offset)
  u64* keys = Sg + 1024;                              // 133,200 u64
  // total ws use ~75 MB

  k_prep<<<dim3(9392), 256, 0, stream>>>(feat, mdw, clsw, clsb, offw, offb, Fp, WfA, hwp, hb, Sg);
  k_conv3_mfma<<<dim3(464), 512, 0, stream>>>(Fp, WfA, mdb, out0, Sg);
  k_heads<<<dim3(232), 256, 0, stream>>>(out0, hwp, hb, Sg, gamma, beta, dout, keys);
  k_post<<<dim3(8), 1024, 0, stream>>>(keys, dout);
}

// Round 16
// 363.870 us; speedup vs baseline: 1.1139x; 1.0498x over previous
//
#include <hip/hip_runtime.h>
#include <cstdint>

// Geometry: B=8, C=512, H=37, W=50, HW=1850, BHW=14800, anchors A=16650, K1=400
#define BHW_ 14800
#define CHW_ 947200
#define A_   16650
#define OCLS 532800
#define OBOX 799200
#define OKEEP 812000
#define NSTEP 144     // 16 cc-chunks * 9 khw

typedef unsigned int u32;
typedef unsigned long long u64;
typedef _Float16 f16x8 __attribute__((ext_vector_type(8)));
typedef float f32x4 __attribute__((ext_vector_type(4)));

union U8 { f16x8 v; u32 u[4]; };
union H2U { _Float16 f; unsigned short u; };

__device__ __forceinline__ unsigned int fkey(float f){
  unsigned int u = __float_as_uint(f);
  return (u & 0x80000000u) ? ~u : (u | 0x80000000u);
}

// anchors exactly as numpy: w=(16*s)/sqrt(r), h=(16*s)*sqrt(r), f64 then f32 cast
__device__ __forceinline__ void anchor_corners(int x, int y, int kk,
                                               float& ax1, float& ay1, float& ax2, float& ay2){
  int si = kk % 3, ri = kk / 3;
  double rv = (ri==0) ? 0.5 : ((ri==1) ? 1.0 : 2.0);
  double sr = sqrt(rv);
  double fs = 128.0 * (double)(si+1);
  double h = fs * sr, w = fs / sr;
  double cx = (double)(x*16 + 8), cy = (double)(y*16 + 8);
  ax1 = (float)(cx - w*0.5); ay1 = (float)(cy - h*0.5);
  ax2 = (float)(cx + w*0.5); ay2 = (float)(cy + h*0.5);
}

// --- merged prepass:
//  [0,8112)      feature -> packed u32 planes Fp[bc][2028], u32 = (lo16<<16)|hi16; pad = 0
//  [8112,9264)   weight-split, coalesced khw-fastest mapping
//  [9264,9392)   head-pack + zero BN-stat accumulators
__global__ __launch_bounds__(256) void k_prep(const float* __restrict__ feat, const float* __restrict__ mdw,
                                              const float* __restrict__ cw, const float* __restrict__ cb,
                                              const float* __restrict__ ow, const float* __restrict__ ob,
                                              u32* __restrict__ Fp, _Float16* __restrict__ WfA,
                                              float* __restrict__ hwp, float* __restrict__ hb,
                                              u64* __restrict__ Sg){
  int bid = blockIdx.x;
  if (bid < 8112){
    int q = bid*256 + threadIdx.x;          // < 8*512*507
    int p4 = (q % 507)*4;
    int bc = q / 507;
    u32 outw[4];
    #pragma unroll
    for (int e = 0; e < 4; ++e){
      int padpos = p4 + e;
      int yp = padpos/52, xp = padpos - yp*52;
      float v = 0.f;
      int y = yp - 1, x = xp - 1;
      if ((unsigned)y < 37u && (unsigned)x < 50u) v = feat[(size_t)bc*1850 + y*50 + x];
      _Float16 h = (_Float16)v;
      _Float16 l = (_Float16)(v - (float)h);
      H2U hu, lu; hu.f = h; lu.f = l;
      outw[e] = ((u32)lu.u << 16) | (u32)hu.u;
    }
    *(uint4*)&Fp[(size_t)bc*2028 + p4] = *(uint4*)outw;
  } else if (bid < 9264){
    int u = (bid - 8112)*256 + threadIdx.x; // < 294912 = 16*4*4*128*9
    int khw = u % 9;
    int v = u / 9;                          // < 32768
    int o7  = v & 127;
    int l4g = (v >> 7) & 3;
    int ot  = (v >> 9) & 3;
    int cc  = v >> 11;                      // 0..15
    int o = ot*128 + o7;
    int s = cc*9 + khw;
    f16x8 hi, lo;
    #pragma unroll
    for (int j = 0; j < 8; ++j){
      float val = mdw[(size_t)(o*512 + cc*32 + l4g*8 + j)*9 + khw];
      _Float16 h = (_Float16)val;
      hi[j] = h; lo[j] = (_Float16)(val - (float)h);
    }
    size_t base = ((size_t)(s*4 + ot)*1024 + (size_t)(l4g*2)*128 + o7)*8;
    *(f16x8*)&WfA[base] = hi;
    *(f16x8*)&WfA[base + 1024] = lo;        // +128 chunks (hl=1)
  } else {
    int t = (bid - 9264)*256 + threadIdx.x; // < 32768
    if (t < 64) hb[t] = (t < 18) ? cb[t] : (t < 54 ? ob[t-18] : 0.f);
    if (t < 1024) Sg[t] = 0ull;             // zero BN-stat accumulators every call
    int r = t & 63, ci = t >> 6;
    hwp[t] = (r < 18) ? cw[r*512 + ci] : (r < 54 ? ow[(r-18)*512 + ci] : 0.f);
  }
}

// --- 3x3 conv, implicit GEMM, f16x2-split MFMA. 512 threads = 8 waves of 64o x 32n.
// BM=BN=128, BK=32. A: gload_lds staged. B: global->reg early, pack->LDS late (T14).
// One __syncthreads per step; LDS dbuf 64KB -> 2 blocks/CU. [r7 conv: 232us @ MfmaUtil 41%]
// BN stats in the epilogue via deterministic fixed-point i64 atomics; f32 math (f64 was
// the r15 regression): float ops deterministic + integer adds associative -> replay-safe.
__global__ __launch_bounds__(512, 2) void k_conv3_mfma(const u32* __restrict__ Fp,
                                                       const _Float16* __restrict__ WfA,
                                                       const float* __restrict__ mdb,
                                                       float* __restrict__ out0,
                                                       u64* __restrict__ Sg){
  __shared__ _Float16 Abuf[2][8192];
  __shared__ _Float16 Bbuf[2][8192];
  __shared__ u64 Sred[256];   // [128 ch][2: sum, sumsq]
  const int tid = threadIdx.x;
  if (tid < 256) Sred[tid] = 0ull;
  // otile-major XCD grouping: each XCD's blocks share one otile's A slab (2.36MB, L2-fits)
  int flat = blockIdx.x;
  int xcd = flat & 7, sub = flat >> 3;
  int swz = xcd * 58 + sub;
  int otile = swz / 116;
  int ntile = swz - otile*116;

  // B staging role: pos = tid&127, k-octet group kg8 = tid>>7 (0..3)
  const int bpos = tid & 127, kg8 = tid >> 7;
  int n = ntile*128 + bpos; if (n >= BHW_) n = BHW_ - 1;
  int nb = n/1850; int rem = n - nb*1850; int ny = rem/50; int nx = rem - ny*50;
  const u32* bbase = Fp + (size_t)(nb*512 + kg8*8)*2028 + (ny+1)*52 + (nx+1);

  u32 R[8];
  auto loadB = [&](int s){
    int cc = s/9, khw = s - cc*9;
    int dy = khw/3 - 1, dx = khw - (khw/3)*3 - 1;
    const u32* src = bbase + (size_t)cc*32*2028 + dy*52 + dx;
    #pragma unroll
    for (int i = 0; i < 8; ++i) R[i] = src[(size_t)i*2028];
  };
  auto writeB = [&](int cur){
    U8 hi, lo;
    #pragma unroll
    for (int p = 0; p < 4; ++p){
      u32 P0 = R[2*p], P1 = R[2*p+1];
      hi.u[p] = (P1 << 16) | (P0 & 0xFFFFu);
      lo.u[p] = (P0 >> 16) | (P1 & 0xFFFF0000u);
    }
    *(f16x8*)&Bbuf[cur][(size_t)((kg8*2 + 0)*128 + bpos)*8] = hi.v;
    *(f16x8*)&Bbuf[cur][(size_t)((kg8*2 + 1)*128 + bpos)*8] = lo.v;
  };
  auto stageA = [&](int s, int cur){
    const _Float16* g = WfA + ((size_t)(s*4 + otile)*1024 + tid)*8;
    _Float16* l = &Abuf[cur][(size_t)tid*8];
    __builtin_amdgcn_global_load_lds((const __attribute__((address_space(1))) void*)g,
                                     (__attribute__((address_space(3))) void*)l, 16, 0, 0);
    __builtin_amdgcn_global_load_lds((const __attribute__((address_space(1))) void*)(g + 4096),
                                     (__attribute__((address_space(3))) void*)(l + 4096), 16, 0, 0);
  };

  // compute role: 8 waves -> wm = w>>2 (o-half), wn = w&3 (n-quarter)
  const int w = tid >> 6, lane = tid & 63;
  const int wm = w >> 2, wn = w & 3;
  const int l15 = lane & 15, l4 = lane >> 4;

  f32x4 acc[4][2] = {};

  auto compute = [&](int cur){
    f16x8 ah[4], al[4], bh[2], bl[2];
    #pragma unroll
    for (int mf = 0; mf < 4; ++mf){
      int m = wm*64 + mf*16 + l15;
      ah[mf] = *(const f16x8*)&Abuf[cur][(size_t)((l4*2 + 0)*128 + m)*8];
      al[mf] = *(const f16x8*)&Abuf[cur][(size_t)((l4*2 + 1)*128 + m)*8];
    }
    #pragma unroll
    for (int nf = 0; nf < 2; ++nf){
      int nn = wn*32 + nf*16 + l15;
      bh[nf] = *(const f16x8*)&Bbuf[cur][(size_t)((l4*2 + 0)*128 + nn)*8];
      bl[nf] = *(const f16x8*)&Bbuf[cur][(size_t)((l4*2 + 1)*128 + nn)*8];
    }
    #pragma unroll
    for (int mf = 0; mf < 4; ++mf)
      #pragma unroll
      for (int nf = 0; nf < 2; ++nf){
        acc[mf][nf] = __builtin_amdgcn_mfma_f32_16x16x32_f16(ah[mf], bh[nf], acc[mf][nf], 0,0,0);
        acc[mf][nf] = __builtin_amdgcn_mfma_f32_16x16x32_f16(ah[mf], bl[nf], acc[mf][nf], 0,0,0);
        acc[mf][nf] = __builtin_amdgcn_mfma_f32_16x16x32_f16(al[mf], bh[nf], acc[mf][nf], 0,0,0);
      }
  };

  // prologue
  loadB(0);
  stageA(0, 0);
  writeB(0);                 // waits on R; gload_lds drained by the barrier
  __syncthreads();

  int cur = 0;
  for (int s = 0; s < NSTEP; ++s){
    if (s + 1 < NSTEP){
      loadB(s+1);            // issue early: global->reg, consumed after compute
      stageA(s+1, cur^1);    // async -> other buffer
      __builtin_amdgcn_sched_barrier(0);
    }
    compute(cur);
    if (s + 1 < NSTEP) writeB(cur^1);
    __syncthreads();
    cur ^= 1;
  }

  // epilogue: store C and accumulate BN stats.
  #pragma unroll
  for (int nf = 0; nf < 2; ++nf){
    int ng = ntile*128 + wn*32 + nf*16 + l15;
    if (ng >= BHW_) continue;
    int b2 = ng/1850; int rem2 = ng - b2*1850;
    #pragma unroll
    for (int mf = 0; mf < 4; ++mf){
      int o0 = otile*128 + wm*64 + mf*16 + l4*4;
      #pragma unroll
      for (int r = 0; r < 4; ++r){
        out0[(size_t)b2*CHW_ + (size_t)(o0 + r)*1850 + rem2] = acc[mf][nf][r] + mdb[o0 + r];
      }
    }
  }
  // BN stats: fixed point (v*2^24, v^2*2^30), all-f32 math (deterministic), i64 sums.
  #pragma unroll
  for (int mf = 0; mf < 4; ++mf){
    int o0 = otile*128 + wm*64 + mf*16 + l4*4;
    #pragma unroll
    for (int r = 0; r < 4; ++r){
      float bias = mdb[o0 + r];
      long long s = 0, s2 = 0;
      #pragma unroll
      for (int nf = 0; nf < 2; ++nf){
        int ng = ntile*128 + wn*32 + nf*16 + l15;
        if (ng < BHW_){
          float v = acc[mf][nf][r] + bias;
          s  += llrintf(v * 16777216.0f);
          s2 += llrintf((v * v) * 1073741824.0f);
        }
      }
      #pragma unroll
      for (int m2 = 1; m2 < 16; m2 <<= 1){
        s  += __shfl_xor(s,  m2, 64);
        s2 += __shfl_xor(s2, m2, 64);
      }
      if (l15 == 0){
        int cloc = wm*64 + mf*16 + l4*4 + r;
        atomicAdd(&Sred[cloc*2],   (u64)s);
        atomicAdd(&Sred[cloc*2+1], (u64)s2);
      }
    }
  }
  __syncthreads();
  if (tid < 256) atomicAdd(&Sg[otile*256 + tid], Sred[tid]);
}

// --- head GEMM (32-position tiles, 463 blocks for occupancy) with fused BN-stat finalize
//     + BN+ReLU staging + score-key emission. Accumulation order identical to 64-pos version.
__global__ __launch_bounds__(256) void k_heads(const float* __restrict__ out0, const float* __restrict__ hwp,
                                               const float* __restrict__ hb, const u64* __restrict__ Sg,
                                               const float* __restrict__ gamma,
                                               const float* __restrict__ beta, float* __restrict__ dout,
                                               u64* __restrict__ keys){
#pragma clang fp contract(off)
  __shared__ float As[16][64];
  __shared__ float Bs[16][32];
  __shared__ float bnmL[512], bnrL[512];
  __shared__ int sb[32], sy[32], sx[32];
  int tid = threadIdx.x; int ntile = blockIdx.x;
  // finalize BN stats from fixed-point sums (same formula as the old f64 k_bnstats)
  for (int c = tid; c < 512; c += 256){
    double s  = (double)(long long)Sg[c*2]   / 16777216.0;
    double s2 = (double)(long long)Sg[c*2+1] / 1073741824.0;
    double m = s / 14800.0;
    double var = s2 / 14800.0 - m*m;
    bnmL[c] = (float)m;
    bnrL[c] = 1.0f / sqrtf((float)var + 1e-5f);
  }
  if (tid < 32){
    int n = ntile*32 + tid;
    if (n < BHW_){ int b = n/1850; int r = n - b*1850; int y = r/50; sb[tid]=b; sy[tid]=y; sx[tid]=r - y*50; }
    else { sb[tid] = -1; sy[tid] = 0; sx[tid] = 0; }
  }
  __syncthreads();
  float acc[4][2] = {};
  const int tx = tid & 15, ty = tid >> 4;
  const int lci = tid >> 4, lo4 = (tid & 15) * 4, lo2 = (tid & 15) * 2;
  for (int ct = 0; ct < 32; ++ct){
    int cib = ct*16;
    float4 av = *(const float4*)(hwp + (cib + lci)*64 + lo4);
    float2 bv; float* bp = (float*)&bv;
    int cig = cib + lci;
    float gm = gamma[cig], mm = bnmL[cig], rr = bnrL[cig], bt = beta[cig];
    #pragma unroll
    for (int j = 0; j < 2; ++j){
      int nn = lo2 + j; int b = sb[nn];
      float v = 0.f;
      if (b >= 0){
        float x = out0[(size_t)b*CHW_ + (size_t)cig*1850 + sy[nn]*50 + sx[nn]];
        float y = gm * (x - mm);
        y = y * rr;
        y = y + bt;
        v = fmaxf(y, 0.f);
      }
      bp[j] = v;
    }
    __syncthreads();
    *(float4*)&As[lci][lo4] = av;
    *(float2*)&Bs[lci][lo2] = bv;
    __syncthreads();
    #pragma unroll
    for (int k = 0; k < 16; ++k){
      float4 a4 = *(const float4*)&As[k][ty*4];
      float2 b2 = *(const float2*)&Bs[k][tx*2];
      const float* ap = (const float*)&a4; const float* bq = (const float*)&b2;
      #pragma unroll
      for (int i = 0; i < 4; ++i)
        #pragma unroll
        for (int j = 0; j < 2; ++j)
          acc[i][j] = fmaf(ap[i], bq[j], acc[i][j]);
    }
  }
  #pragma unroll
  for (int i = 0; i < 4; ++i){
    int r = ty*4 + i;
    if (r >= 54) continue;
    float bias = hb[r];
    #pragma unroll
    for (int j = 0; j < 2; ++j){
      int nl = tx*2 + j;
      int b = sb[nl];
      if (b < 0) continue;
      int pos = sy[nl]*50 + sx[nl];
      float v = acc[i][j] + bias;
      if (r < 18){
        int kk = r >> 1, cc = r & 1;
        dout[OCLS + ((size_t)b*A_ + pos*9 + kk)*2 + cc] = v;
      } else {
        int r2 = r - 18, kk = r2 >> 2, cc = r2 & 3;
        dout[((size_t)b*A_ + pos*9 + kk)*4 + cc] = v;
      }
    }
  }
  if (ty < 5){
    #pragma unroll
    for (int i = 0; i < 4; i += 2){
      int r = ty*4 + i;
      if (r >= 18) continue;
      int kk = r >> 1;
      float b0 = hb[r], b1 = hb[r+1];
      #pragma unroll
      for (int j = 0; j < 2; ++j){
        int nl = tx*2 + j;
        int b = sb[nl];
        if (b < 0) continue;
        float c0 = acc[i][j] + b0;
        float c1 = acc[i+1][j] + b1;
        float d = c1 - c0;
        float ax1, ay1, ax2, ay2;
        anchor_corners(sx[nl], sy[nl], kk, ax1, ay1, ax2, ay2);
        bool valid = (ax1 >= 0.f) && (ay1 >= 0.f) && (ax2 < 800.f) && (ay2 < 592.f);
        unsigned a = (unsigned)(sy[nl]*50 + sx[nl])*9u + (unsigned)kk;
        u64 key = valid ? (((u64)fkey(d) << 32) | (u64)(~a)) : 0ull;
        keys[(size_t)b*A_ + a] = key;
      }
    }
  }
}

// --- fused deterministic post: 2-level histogram threshold -> LDS compact -> LDS rank
//     -> decode -> adjacency NMS. NO intra-kernel global scratch (r8 lesson).
__global__ __launch_bounds__(1024) void k_post(const u64* __restrict__ keys,
                                               float* __restrict__ dout){
#pragma clang fp contract(off)
  __shared__ u32 hist[4096];
  __shared__ u32 sp[1024];
  __shared__ u64 selbuf[4096];
  __shared__ u64 stopk[400];
  __shared__ u32 adj32[6400];
  __shared__ float X1[400], Y1[400], X2[400], Y2[400], AR[400];
  __shared__ u32 ssup[13];
  __shared__ u32 s_t1, s_base1, s_t2, scnt;
  int b = blockIdx.x, tid = threadIdx.x;
  const u64* kb = keys + (size_t)b*A_;

  // ---- pass 1: histogram of key bits [52,63] over nonzero keys
  for (int i = tid; i < 4096; i += 1024) hist[i] = 0u;
  if (tid == 0) scnt = 0u;
  __syncthreads();
  for (int i = tid; i < A_; i += 1024){
    u64 k = kb[i];
    if (k) atomicAdd(&hist[(u32)(k >> 52)], 1u);
  }
  __syncthreads();
  {
    u32 p = hist[tid*4] + hist[tid*4+1] + hist[tid*4+2] + hist[tid*4+3];
    sp[tid] = p; __syncthreads();
    for (int off = 1; off < 1024; off <<= 1){
      u32 v = sp[tid] + ((tid + off < 1024) ? sp[tid + off] : 0u);
      __syncthreads(); sp[tid] = v; __syncthreads();
    }
    if (sp[tid] >= 400u && (tid == 1023 || sp[tid+1] < 400u)){
      u32 cum = (tid == 1023) ? 0u : sp[tid+1];
      for (int bb = tid*4 + 3; bb >= tid*4; --bb){
        cum += hist[bb];
        if (cum >= 400u){ s_t1 = (u32)bb; s_base1 = cum - hist[bb]; break; }
      }
    }
  }
  __syncthreads();
  const u32 t1 = s_t1;
  const u32 need2 = 400u - s_base1;   // >= 1

  // ---- pass 2: histogram of bits [40,51] among keys whose top-12 == t1
  __syncthreads();
  for (int i = tid; i < 4096; i += 1024) hist[i] = 0u;
  __syncthreads();
  for (int i = tid; i < A_; i += 1024){
    u64 k = kb[i];
    if (k && (u32)(k >> 52) == t1) atomicAdd(&hist[(u32)(k >> 40) & 0xFFFu], 1u);
  }
  __syncthreads();
  {
    u32 p = hist[tid*4] + hist[tid*4+1] + hist[tid*4+2] + hist[tid*4+3];
    sp[tid] = p; __syncthreads();
    for (int off = 1; off < 1024; off <<= 1){
      u32 v = sp[tid] + ((tid + off < 1024) ? sp[tid + off] : 0u);
      __syncthreads(); sp[tid] = v; __syncthreads();
    }
    if (sp[tid] >= need2 && (tid == 1023 || sp[tid+1] < need2)){
      u32 cum = (tid == 1023) ? 0u : sp[tid+1];
      for (int bb = tid*4 + 3; bb >= tid*4; --bb){
        cum += hist[bb];
        if (cum >= need2){ s_t2 = (u32)bb; break; }
      }
    }
  }
  __syncthreads();
  const u32 t2 = s_t2;

  // ---- compact selected keys into LDS (order nondeterministic; rank fixes it)
  for (int i = tid; i < A_; i += 1024){
    u64 k = kb[i];
    if (!k) continue;
    u32 top = (u32)(k >> 52);
    bool sel = (top > t1) || (top == t1 && ((u32)(k >> 40) & 0xFFFu) >= t2);
    if (sel){
      u32 pidx = atomicAdd(&scnt, 1u);
      if (pidx < 4096u) selbuf[pidx] = k;
    }
  }
  __syncthreads();
  int C = min((int)scnt, 4096);

  // ---- exact in-LDS rank-by-counting -> ordered top-400
  for (int i = tid; i < C; i += 1024){
    u64 my = selbuf[i];
    int c = 0;
    for (int j = 0; j < C; ++j) c += (selbuf[j] > my) ? 1 : 0;
    if (c < 400) stopk[c] = my;
  }
  __syncthreads();

  // ---- decode boxes + adjacency bitmask
  for (int i = tid; i < 6400; i += 1024) adj32[i] = 0u;
  if (tid < 400){
    u64 key = stopk[tid];
    unsigned a = ~(unsigned)(key & 0xFFFFFFFFull);
    int pos = a/9; int kk = a - pos*9;
    int y = pos/50; int x = pos - y*50;
    float ax1, ay1, ax2, ay2;
    anchor_corners(x, y, kk, ax1, ay1, ax2, ay2);
    float xa = (ax1 + ax2) * 0.5f;
    float ya = (ay1 + ay2) * 0.5f;
    float wa = ax2 - ax1 + 1.0f;
    float ha = ay2 - ay1 + 1.0f;
    const float* t = dout + ((size_t)b*A_ + a)*4;
    float t0 = t[0], t1f = t[1], t2f = t[2], t3 = t[3];
    float xc = t0 * wa + xa;
    float yc = t1f * ha + ya;
    float bw = wa * expf(t2f);
    float bh = ha * expf(t3);
    float bx1 = xc - bw*0.5f, by1 = yc - bh*0.5f;
    float bx2 = xc + bw*0.5f, by2 = yc + bh*0.5f;
    float* bo = dout + OBOX + ((size_t)b*400 + tid)*4;
    bo[0] = bx1; bo[1] = by1; bo[2] = bx2; bo[3] = by2;
    float tx1 = truncf(bx1), ty1 = truncf(by1), tx2 = truncf(bx2), ty2 = truncf(by2);
    X1[tid] = tx1; Y1[tid] = ty1; X2[tid] = tx2; Y2[tid] = ty2;
    AR[tid] = (tx2 - tx1 + 1.0f) * (ty2 - ty1 + 1.0f);
  }
  __syncthreads();
  for (int q = tid; q < 160000; q += 1024){
    int i = q / 400, j = q - i*400;
    if (j > i){
      float iw = fminf(X2[i], X2[j]) - fmaxf(X1[i], X1[j]) + 1.0f; iw = fmaxf(iw, 0.f);
      float ih = fminf(Y2[i], Y2[j]) - fmaxf(Y1[i], Y1[j]) + 1.0f; ih = fmaxf(ih, 0.f);
      float inter = iw * ih;
      float iou = inter / ((AR[i] + AR[j]) - inter);
      if (iou > 0.6f) atomicOr(&adj32[i*16 + (j >> 5)], 1u << (j & 31));
    }
  }
  __syncthreads();
  // ---- serial greedy over the adjacency bitmask (wave 0, lockstep)
  if (tid < 64){
    u32 sup = 0;
    for (int i = 0; i < 399; ++i){
      u32 a = (tid < 13) ? adj32[i*16 + tid] : 0u;
      u32 so = __shfl(sup, i >> 5);
      if (!((so >> (i & 31)) & 1u)) sup |= a;
    }
    if (tid < 13) ssup[tid] = sup;
  }
  __syncthreads();
  if (tid < 400)
    dout[OKEEP + (size_t)b*400 + tid] = ((ssup[tid >> 5] >> (tid & 31)) & 1u) ? 0.f : 1.f;
}

extern "C" void kernel_launch(void* const* d_in, const int* in_sizes, int n_in,
                              void* d_out, int out_size, void* d_ws, size_t ws_size,
                              hipStream_t stream){
  const float* feat  = (const float*)d_in[0];
  const float* mdw   = (const float*)d_in[1];
  const float* mdb   = (const float*)d_in[2];
  const float* gamma = (const float*)d_in[3];
  const float* beta  = (const float*)d_in[4];
  const float* clsw  = (const float*)d_in[5];
  const float* clsb  = (const float*)d_in[6];
  const float* offw  = (const float*)d_in[7];
  const float* offb  = (const float*)d_in[8];
  float* dout = (float*)d_out;
  float* ws = (float*)d_ws;

  float* out0 = ws;                                   // 7,577,600 f32
  _Float16* WfA = (_Float16*)(out0 + 7577600);        // 4,718,592 f16 (2,359,296 f32)
  u32* Fp = (u32*)(out0 + 7577600 + 2359296);         // 8,306,688 u32
  float* hwp = (float*)(Fp + 8306688);                // 32,768
  float* hb  = hwp + 32768;                           // 64
  u64* Sg = (u64*)(hb + 64);                          // 1024 u64
  u64* keys = Sg + 1024;                              // 133,200 u64
  // total ws use ~75 MB

  k_prep<<<dim3(9392), 256, 0, stream>>>(feat, mdw, clsw, clsb, offw, offb, Fp, WfA, hwp, hb, Sg);
  k_conv3_mfma<<<dim3(464), 512, 0, stream>>>(Fp, WfA, mdb, out0, Sg);
  k_heads<<<dim3(463), 256, 0, stream>>>(out0, hwp, hb, Sg, gamma, beta, dout, keys);
  k_post<<<dim3(8), 1024, 0, stream>>>(keys, dout);
}